// Round 11
// baseline (198.814 us; speedup 1.0000x reference)
//
#include <hip/hip_runtime.h>
#include <hip/hip_fp16.h>

#define L_SEQ 4096
#define BATCH 4
#define DIM 512
#define M_ROWS (L_SEQ * BATCH)          // 16384
#define SCALE 0.04419417382415922f      // 1/sqrt(512)
#define SLS 4097                         // star logits per batch (L+1)

typedef __attribute__((ext_vector_type(4))) float f32x4;
typedef __attribute__((ext_vector_type(8))) _Float16 f16x8;
typedef __attribute__((ext_vector_type(4))) _Float16 f16x4;

__device__ inline void gload16(const void* g, void* l) {
    __builtin_amdgcn_global_load_lds(
        (const __attribute__((address_space(1))) void*)g,
        (__attribute__((address_space(3))) void*)l, 16, 0, 0);
}

__device__ inline float wred_sum(float s) {
#pragma unroll
    for (int o = 32; o; o >>= 1) s += __shfl_xor(s, o);
    return s;
}
__device__ inline float wred_max(float s) {
#pragma unroll
    for (int o = 32; o; o >>= 1) s = fmaxf(s, __shfl_xor(s, o));
    return s;
}

// ------- prep: f32->f16 conversions + bias pack + relay k/v proj + star zero -------
#define PREP_NV   1048576                // f16x8 items per tensor (8M elems / 8)
#define PREP_XE_B 8192
#define PREP_W_B  768
__global__ __launch_bounds__(256) void prep(
    const float* __restrict__ x, const float* __restrict__ e,
    const float* __restrict__ Wq, const float* __restrict__ Wk,
    const float* __restrict__ Wv, const float* __restrict__ Wo,
    const float* __restrict__ bq, const float* __restrict__ bk, const float* __restrict__ bv,
    const float* __restrict__ relay,
    _Float16* __restrict__ xh, _Float16* __restrict__ eh,
    _Float16* __restrict__ Wqkv, _Float16* __restrict__ Wof, float* __restrict__ bqkv,
    float* __restrict__ krvr, float* __restrict__ star)
{
    const int bid = blockIdx.x;
    if (bid < PREP_XE_B) {                   // x,e: 2*PREP_NV f16x8 items
        int j = bid * 256 + threadIdx.x;
        const float* src; _Float16* dst;
        if (j < PREP_NV) { src = x; dst = xh; } else { src = e; dst = eh; j -= PREP_NV; }
        const float* p = src + (size_t)j * 8;
        float4 a = *(const float4*)p, b = *(const float4*)(p + 4);
        f16x8 h = { (_Float16)a.x, (_Float16)a.y, (_Float16)a.z, (_Float16)a.w,
                    (_Float16)b.x, (_Float16)b.y, (_Float16)b.z, (_Float16)b.w };
        *(f16x8*)(dst + (size_t)j * 8) = h;
    } else if (bid < PREP_XE_B + PREP_W_B) { // weights: 196608 f16x4 items
        const int w = (bid - PREP_XE_B) * 256 + threadIdx.x;
        const int o = w * 4, r = o >> 9, c = o & 511;
        const float* W = (r < 512) ? Wq : (r < 1024 ? Wk : Wv);
        float4 v = *(const float4*)(W + (size_t)(r & 511) * 512 + c);
        *(f16x4*)(Wqkv + o) = f16x4{ (_Float16)v.x, (_Float16)v.y, (_Float16)v.z, (_Float16)v.w };
        if (o < 262144) {
            float4 u = *(const float4*)(Wo + o);
            *(f16x4*)(Wof + o) = f16x4{ (_Float16)u.x, (_Float16)u.y, (_Float16)u.z, (_Float16)u.w };
        }
        if (w < 1536) bqkv[w] = (w < 512) ? bq[w] : (w < 1024 ? bk[w - 512] : bv[w - 1024]);
    } else {                                 // relay k/v projection (fp32), wave-per-output
        const int o = ((bid - PREP_XE_B - PREP_W_B) << 2) + (threadIdx.x >> 6);   // 0..4095
        const int lane = threadIdx.x & 63;
        const int sel = o >> 11, rem = o & 2047, b = rem >> 9, j = rem & 511;
        const float* W = sel ? Wv : Wk;
        const float* wr = W + (size_t)j * 512 + lane * 8;
        const float* rp = relay + (size_t)b * 512 + lane * 8;
        float4 w0 = *(const float4*)wr,  w1 = *(const float4*)(wr + 4);
        float4 r0 = *(const float4*)rp,  r1 = *(const float4*)(rp + 4);
        float s = w0.x * r0.x + w0.y * r0.y + w0.z * r0.z + w0.w * r0.w
                + w1.x * r1.x + w1.y * r1.y + w1.z * r1.z + w1.w * r1.w;
        s = wred_sum(s);
        if (lane == 0) {
            krvr[o] = s + (sel ? bv[j] : bk[j]);
            if (o < 2048) star[o] = 0.f;
        }
    }
}

// ------- 2-phase 128x128 GEMM, 4-deep ring, SINGLE barrier per K-step --------
// C[M,cstride] <- A[M,512] * W[N,512]^T + bias. K=512 (16 slices of 32).
// r11: depth-4 ring (64 KB) lets body t restage tile t+3 into slot (t+3)&3,
// whose only readers were step t-1 — and any wave's step-(t-1) ds_reads are
// retired before it reaches barrier(t) (every read feeds an MFMA; DS retires
// in order; the last consumer's lgkmcnt wait covers all). So the second
// barrier + lgkmcnt(0) drain are dropped. Per step:
//   vmcnt(8) -> s_barrier -> stage(t+3) -> 8 ds_read || 16 MFMA.
// Ledger: prologue stages 0,1,2 (12 loads); at step t outstanding = t+1,t+2
// -> vmcnt(8) t<=13, vmcnt(4) t=14, vmcnt(0) t=15. Epilogue via LDS bounce.
struct GemmP {
    const _Float16* A;      // [M,512]
    const _Float16* W;      // [N,512] (pre-offset)
    const float*    bias;   // pre-offset
    void*           C;
    int             cstride;
    int             ncols;  // col tiles = N/128
};

template<int OUT16>
__global__ __launch_bounds__(256) void gemm2p(GemmP g0, GemmP g1, int n0, int cpx)
{
    __shared__ __align__(16) char smem[65536];
    _Float16* lAb = (_Float16*)smem;              // 4 slices x 4096 elems (32 KB)
    _Float16* lBb = (_Float16*)(smem + 32768);    // 4 slices x 4096 elems

    const int bid = blockIdx.x;
    const int swz = (bid & 7) * cpx + (bid >> 3);        // bijective: grid%8==0
    const GemmP g = (swz < n0) ? g0 : g1;
    const int l  = (swz < n0) ? swz : swz - n0;
    const int mt = l / g.ncols, nt = l % g.ncols;
    const int row0 = mt * 128, col0 = nt * 128;

    const int tid = threadIdx.x;
    const int wave = tid >> 6, lane = tid & 63;
    const int wm = (wave >> 1) * 64, wn = (wave & 1) * 64;

    f32x4 acc[4][4];
#pragma unroll
    for (int i = 0; i < 4; ++i)
#pragma unroll
        for (int j = 0; j < 4; ++j) acc[i][j] = (f32x4)0.f;

    // staging: two rounds of 256 16B-slots; LDS dest LINEAR,
    // global source col-slot XOR-swizzled (both-sides involution).
    const int idx0 = tid, idx1 = 256 + tid;
    const int r0_ = idx0 >> 2, c0_ = ((idx0 & 3) ^ ((idx0 >> 3) & 3)) * 8;
    const int r1_ = idx1 >> 2, c1_ = ((idx1 & 3) ^ ((idx1 >> 3) & 3)) * 8;
    const int ldsb0 = (wave * 64) * 8;
    const int ldsb1 = (256 + wave * 64) * 8;

    auto stage = [&](int buf, int t) {
        const int k0 = t << 5;
        gload16(g.A + (size_t)(row0 + r0_) * 512 + k0 + c0_, lAb + buf * 4096 + ldsb0);
        gload16(g.A + (size_t)(row0 + r1_) * 512 + k0 + c1_, lAb + buf * 4096 + ldsb1);
        gload16(g.W + (size_t)(col0 + r0_) * 512 + k0 + c0_, lBb + buf * 4096 + ldsb0);
        gload16(g.W + (size_t)(col0 + r1_) * 512 + k0 + c1_, lBb + buf * 4096 + ldsb1);
    };
    stage(0, 0);
    stage(1, 1);
    stage(2, 2);          // 12 loads in flight

    const int rslot = ((lane >> 4) ^ ((lane >> 1) & 3)) * 8;
    const int arb = (wm + (lane & 15)) * 32 + rslot;
    const int brb = (wn + (lane & 15)) * 32 + rslot;

    int rs = 0;
#pragma unroll 1
    for (int t = 0; t < 16; ++t) {
        if (t < 14)       asm volatile("s_waitcnt vmcnt(8)" ::: "memory");
        else if (t == 14) asm volatile("s_waitcnt vmcnt(4)" ::: "memory");
        else              asm volatile("s_waitcnt vmcnt(0)" ::: "memory");
        asm volatile("s_barrier" ::: "memory");       // tile t staged (all waves' vmcnt
                                                      // precede their barrier arrival)
        if (t + 3 < 16) stage((t + 3) & 3, t + 3);    // slot (t+3)&3: readers were step
                                                      // t-1, provably retired pre-barrier
        f16x8 af[4], bfr[4];
#pragma unroll
        for (int i = 0; i < 4; ++i) af[i]  = *(const f16x8*)(lAb + rs * 4096 + arb + i * 512);
#pragma unroll
        for (int i = 0; i < 4; ++i) bfr[i] = *(const f16x8*)(lBb + rs * 4096 + brb + i * 512);
        __builtin_amdgcn_s_setprio(1);
#pragma unroll
        for (int mi = 0; mi < 4; ++mi)
#pragma unroll
            for (int ni = 0; ni < 4; ++ni)
                acc[mi][ni] = __builtin_amdgcn_mfma_f32_16x16x32_f16(
                    af[mi], bfr[ni], acc[mi][ni], 0, 0, 0);
        __builtin_amdgcn_s_setprio(0);
        rs = (rs + 1) & 3;
    }
    // ring LDS dead after all waves pass the LAST barrier? The last reads are
    // step-15's; the epilogue below starts with a __syncthreads AFTER writes to
    // the bounce region, and every wave's step-15 reads are consumed by its own
    // MFMAs before it writes the bounce (register dependency). Safe.

    const int h = lane >> 4, c = lane & 15;
    if (OUT16) {
        _Float16* ep = (_Float16*)smem;               // [128][136] f16 (34816 B)
#pragma unroll
        for (int mi = 0; mi < 4; ++mi)
#pragma unroll
            for (int ni = 0; ni < 4; ++ni) {
                const float bb = g.bias[col0 + wn + ni * 16 + c];
#pragma unroll
                for (int r = 0; r < 4; ++r)
                    ep[(wm + mi * 16 + h * 4 + r) * 136 + wn + ni * 16 + c] =
                        (_Float16)(acc[mi][ni][r] + bb);
            }
        __syncthreads();
        const int rt = tid >> 4, ct = (tid & 15) * 8;
#pragma unroll
        for (int j = 0; j < 8; ++j) {
            const int row = j * 16 + rt;
            f16x8 v = *(const f16x8*)(ep + row * 136 + ct);
            *(f16x8*)((_Float16*)g.C + (size_t)(row0 + row) * g.cstride + col0 + ct) = v;
        }
    } else {
        float* ep = (float*)smem;                     // [64][132] f32 (33792 B) per pass
#pragma unroll
        for (int pass = 0; pass < 2; ++pass) {
            if ((wm == 0) == (pass == 0)) {           // waves owning these 64 rows write
#pragma unroll
                for (int mi = 0; mi < 4; ++mi)
#pragma unroll
                    for (int ni = 0; ni < 4; ++ni) {
                        const float bb = g.bias[col0 + wn + ni * 16 + c];
#pragma unroll
                        for (int r = 0; r < 4; ++r)
                            ep[(mi * 16 + h * 4 + r) * 132 + wn + ni * 16 + c] =
                                acc[mi][ni][r] + bb;
                    }
            }
            __syncthreads();
            const int rt = tid >> 5, ct4 = (tid & 31) * 4;
#pragma unroll
            for (int j = 0; j < 8; ++j) {
                const int row = j * 8 + rt;
                f32x4 v = *(const f32x4*)(ep + row * 132 + ct4);
                *(f32x4*)((float*)g.C + (size_t)(row0 + pass * 64 + row) * g.cstride + col0 + ct4) = v;
            }
            if (pass == 0) __syncthreads();           // reads done before pass-1 writes
        }
    }
}

// ------- ring attention (one wave per (l,b)) + fused star logits -------
__global__ __launch_bounds__(256) void ring_attn(
    const _Float16* __restrict__ qkv,    // [M,1536] q|k|v
    const _Float16* __restrict__ ekv,    // [M,1024] ke|ve
    const float* __restrict__ krvr,      // [2][B][512]
    const float* __restrict__ relay,     // [B,512]
    _Float16* __restrict__ ring,         // [M,512]
    float* __restrict__ slog)            // [B,SLS]
{
    const int wid = (blockIdx.x << 2) + (threadIdx.x >> 6);   // row r = l*B+b
    const int lane = threadIdx.x & 63;
    const int r = wid, b = r & 3, l = r >> 2;
    const int d0 = lane << 3;

    float q[8], rl[8];
    {
        f16x8 t = *(const f16x8*)(qkv + (size_t)r * 1536 + d0);
#pragma unroll
        for (int i = 0; i < 8; ++i) q[i] = (float)t[i];
        const float* rp = relay + (size_t)b * 512 + d0;
        float4 a = *(const float4*)rp, c = *(const float4*)(rp + 4);
        rl[0] = a.x; rl[1] = a.y; rl[2] = a.z; rl[3] = a.w;
        rl[4] = c.x; rl[5] = c.y; rl[6] = c.z; rl[7] = c.w;
    }
    const bool has0 = (l > 0), has2 = (l < L_SEQ - 1);

    auto dotk = [&](const _Float16* kp) -> float {
        f16x8 t = *(const f16x8*)(kp + d0);
        float s = 0.f;
#pragma unroll
        for (int i = 0; i < 8; ++i) s += q[i] * (float)t[i];
        return wred_sum(s);
    };

    float lg[5];
    lg[0] = has0 ? dotk(qkv + (size_t)(r - 4) * 1536 + 512) : 0.f;  // zero key -> logit 0
    lg[2] = has2 ? dotk(qkv + (size_t)(r + 4) * 1536 + 512) : 0.f;
    lg[3] = dotk(ekv + (size_t)r * 1024);
    {   // self k row: ring logit + star logit (relay . k)
        f16x8 t = *(const f16x8*)(qkv + (size_t)r * 1536 + 512 + d0);
        float s1 = 0.f, s2 = 0.f;
#pragma unroll
        for (int i = 0; i < 8; ++i) { float kf = (float)t[i]; s1 += q[i] * kf; s2 += rl[i] * kf; }
#pragma unroll
        for (int o = 32; o; o >>= 1) { s1 += __shfl_xor(s1, o); s2 += __shfl_xor(s2, o); }
        lg[1] = s1;
        if (lane == 0) slog[(size_t)b * SLS + l] = s2 * SCALE;
    }
    {   // relay key
        const float* kp = krvr + (size_t)b * 512 + d0;
        float s = 0.f;
#pragma unroll
        for (int i = 0; i < 8; ++i) s += q[i] * kp[i];
        lg[4] = wred_sum(s);
    }

    float li[5], m = -1e30f;
#pragma unroll
    for (int w = 0; w < 5; ++w) { li[w] = lg[w] * SCALE; m = fmaxf(m, li[w]); }
    float ew[5], Z = 0.f;
#pragma unroll
    for (int w = 0; w < 5; ++w) { ew[w] = expf(li[w] - m); Z += ew[w]; }
    const float inv = 1.f / Z;

    float o8[8] = {0, 0, 0, 0, 0, 0, 0, 0};
    auto addv = [&](const _Float16* vp, float a) {
        f16x8 t = *(const f16x8*)(vp + d0);
#pragma unroll
        for (int i = 0; i < 8; ++i) o8[i] += a * (float)t[i];
    };
    if (has0) addv(qkv + (size_t)(r - 4) * 1536 + 1024, ew[0] * inv);
    addv(qkv + (size_t)r * 1536 + 1024, ew[1] * inv);
    if (has2) addv(qkv + (size_t)(r + 4) * 1536 + 1024, ew[2] * inv);
    addv(ekv + (size_t)r * 1024 + 512, ew[3] * inv);
    {
        const float* vp = krvr + 2048 + (size_t)b * 512 + d0;
        const float a = ew[4] * inv;
#pragma unroll
        for (int i = 0; i < 8; ++i) o8[i] += a * vp[i];
    }
    f16x8 res;
#pragma unroll
    for (int i = 0; i < 8; ++i) res[i] = (_Float16)o8[i];
    *(f16x8*)(ring + (size_t)r * 512 + d0) = res;
}

// ---------------- star softmax: one 1024-thread block per batch ----------------
__global__ __launch_bounds__(1024) void star_softmax(
    const float* __restrict__ relay, const float* __restrict__ krvr,
    float* __restrict__ slog)
{
    const int b = blockIdx.x, t = threadIdx.x, lane = t & 63, w = t >> 6;
    __shared__ float red[16];
    __shared__ float bc[2];
    float* sl = slog + (size_t)b * SLS;

    float p = 0.f;
    if (t < 512) p = relay[(size_t)b * 512 + t] * krvr[(size_t)b * 512 + t];
    p = wred_sum(p);
    if (lane == 0) red[w] = p;
    __syncthreads();
    if (t == 0) { float s = 0.f; for (int i = 0; i < 16; ++i) s += red[i]; bc[0] = s * SCALE; }
    __syncthreads();
    const float selfl = bc[0];
    __syncthreads();

    float v[4];
#pragma unroll
    for (int i = 0; i < 4; ++i) v[i] = sl[t + i * 1024];

    float m = selfl;
#pragma unroll
    for (int i = 0; i < 4; ++i) m = fmaxf(m, v[i]);
    m = wred_max(m);
    if (lane == 0) red[w] = m;
    __syncthreads();
    if (t == 0) { float mm = red[0]; for (int i = 1; i < 16; ++i) mm = fmaxf(mm, red[i]); bc[1] = mm; }
    __syncthreads();
    m = bc[1];

    float ev[4], z = (t == 0) ? expf(selfl - m) : 0.f;
#pragma unroll
    for (int i = 0; i < 4; ++i) { ev[i] = expf(v[i] - m); z += ev[i]; }
    z = wred_sum(z);
    if (lane == 0) red[w] = z;
    __syncthreads();
    if (t == 0) { float s = 0.f; for (int i = 0; i < 16; ++i) s += red[i]; bc[0] = 1.f / s; }
    __syncthreads();
    const float inv = bc[0];

#pragma unroll
    for (int i = 0; i < 4; ++i) sl[t + i * 1024] = ev[i] * inv;
    if (t == 0) sl[SLS - 1] = expf(selfl - m) * inv;
}

// ------- star weighted V-sum: wave per (chunk,b), 256 blocks x 16 n -------
__global__ __launch_bounds__(256) void star_out(
    const float* __restrict__ slog, const _Float16* __restrict__ qkv,
    const float* __restrict__ krvr, float* __restrict__ star)
{
    const int b = threadIdx.x >> 6, lane = threadIdx.x & 63;
    const int chunk = blockIdx.x;                 // 256 chunks x 16 n each
    const int d0 = lane << 3;
    const float* al = slog + (size_t)b * SLS;
    float acc[8] = {0, 0, 0, 0, 0, 0, 0, 0};
#pragma unroll 4
    for (int i = 0; i < 16; ++i) {
        const int n = chunk * 16 + i;
        const float a = al[n];
        f16x8 v = *(const f16x8*)(qkv + (size_t)(n * 4 + b) * 1536 + 1024 + d0);
#pragma unroll
        for (int j = 0; j < 8; ++j) acc[j] += a * (float)v[j];
    }
    if (chunk == 255) {
        const float a = al[SLS - 1];
        const float* vr = krvr + 2048 + (size_t)b * 512 + d0;
#pragma unroll
        for (int j = 0; j < 8; ++j) acc[j] += a * vr[j];
    }
#pragma unroll
    for (int j = 0; j < 8; ++j) atomicAdd(&star[(size_t)b * 512 + d0 + j], acc[j]);
}

// ---------------- star projection: wave per output ----------------
__global__ __launch_bounds__(256) void star_proj(
    const float* __restrict__ star, const float* __restrict__ Wo,
    const float* __restrict__ bo, float* __restrict__ out1)
{
    const int o = (blockIdx.x << 2) + (threadIdx.x >> 6);   // 0..2047
    const int lane = threadIdx.x & 63;
    const int b = o >> 9, j = o & 511;
    const float* sp = star + (size_t)b * 512 + lane * 8;
    const float* wr = Wo + (size_t)j * 512 + lane * 8;
    float4 w0 = *(const float4*)wr,  w1 = *(const float4*)(wr + 4);
    float4 s0 = *(const float4*)sp,  s1 = *(const float4*)(sp + 4);
    float s = w0.x * s0.x + w0.y * s0.y + w0.z * s0.z + w0.w * s0.w
            + w1.x * s1.x + w1.y * s1.y + w1.z * s1.z + w1.w * s1.w;
    s = wred_sum(s);
    if (lane == 0) out1[o] = s + bo[j];
}

// ---------------- host launch ----------------
extern "C" void kernel_launch(void* const* d_in, const int* in_sizes, int n_in,
                              void* d_out, int out_size, void* d_ws, size_t ws_size,
                              hipStream_t stream) {
    const float* x     = (const float*)d_in[0];
    const float* e     = (const float*)d_in[1];
    const float* relay = (const float*)d_in[2];
    const float* Wq    = (const float*)d_in[3];
    const float* bq    = (const float*)d_in[4];
    const float* Wk    = (const float*)d_in[5];
    const float* bk    = (const float*)d_in[6];
    const float* Wv    = (const float*)d_in[7];
    const float* bv    = (const float*)d_in[8];
    const float* Wo    = (const float*)d_in[9];
    const float* bo    = (const float*)d_in[10];
    float* out = (float*)d_out;

    size_t off = 0;
    auto alloc = [&](size_t bytes) {
        void* p = (char*)d_ws + off;
        off += (bytes + 255) & ~(size_t)255;
        return p;
    };
    _Float16* Wqkv = (_Float16*)alloc((size_t)1536 * 512 * 2);
    _Float16* Wof  = (_Float16*)alloc((size_t)512 * 512 * 2);
    float*    bqkv = (float*)   alloc(1536 * 4);
    _Float16* xh   = (_Float16*)alloc((size_t)M_ROWS * 512 * 2);
    _Float16* eh   = (_Float16*)alloc((size_t)M_ROWS * 512 * 2);
    _Float16* qkv  = (_Float16*)alloc((size_t)M_ROWS * 1536 * 2);
    _Float16* ekv  = (_Float16*)alloc((size_t)M_ROWS * 1024 * 2);
    float*    krvr = (float*)   alloc(2 * 4 * 512 * 4);
    float*    slog = (float*)   alloc((size_t)4 * SLS * 4);
    float*    star = (float*)   alloc(4 * 512 * 4);
    _Float16* ringb = xh;   // alias: xh is dead after the fused qkv/ekv GEMM

    prep<<<PREP_XE_B + PREP_W_B + 1024, 256, 0, stream>>>(
        x, e, Wq, Wk, Wv, Wo, bq, bk, bv, relay,
        xh, eh, Wqkv, Wof, bqkv, krvr, star);

    // fused qkv (128x12=1536 tiles) + ekv (128x8=1024 tiles): 2560 blocks
    GemmP gq { xh, Wqkv,                     bqkv,       qkv, 1536, 12 };
    GemmP ge { eh, Wqkv + (size_t)512 * 512, bqkv + 512, ekv, 1024,  8 };
    gemm2p<1><<<2560, 256, 0, stream>>>(gq, ge, 1536, 320);

    ring_attn<<<M_ROWS / 4, 256, 0, stream>>>(qkv, ekv, krvr, relay, ringb, slog);

    star_softmax<<<4, 1024, 0, stream>>>(relay, krvr, slog);
    star_out<<<256, 256, 0, stream>>>(slog, qkv, krvr, star);

    // out-projection: 128x4 = 512 tiles
    GemmP go { ringb, Wof, bo, out, 512, 4 };
    gemm2p<0><<<512, 256, 0, stream>>>(go, go, 512, 64);

    star_proj<<<512, 256, 0, stream>>>(star, Wo, bo, out + (size_t)M_ROWS * 512);
}

// Round 12
// 197.878 us; speedup vs baseline: 1.0047x; 1.0047x over previous
//
#include <hip/hip_runtime.h>
#include <hip/hip_fp16.h>

#define L_SEQ 4096
#define BATCH 4
#define DIM 512
#define M_ROWS (L_SEQ * BATCH)          // 16384
#define SCALE 0.04419417382415922f      // 1/sqrt(512)
#define SLS 4097                         // star logits per batch (L+1)

typedef __attribute__((ext_vector_type(4))) float f32x4;
typedef __attribute__((ext_vector_type(8))) _Float16 f16x8;
typedef __attribute__((ext_vector_type(4))) _Float16 f16x4;

__device__ inline void gload16(const void* g, void* l) {
    __builtin_amdgcn_global_load_lds(
        (const __attribute__((address_space(1))) void*)g,
        (__attribute__((address_space(3))) void*)l, 16, 0, 0);
}

__device__ inline float wred_sum(float s) {
#pragma unroll
    for (int o = 32; o; o >>= 1) s += __shfl_xor(s, o);
    return s;
}
__device__ inline float wred_max(float s) {
#pragma unroll
    for (int o = 32; o; o >>= 1) s = fmaxf(s, __shfl_xor(s, o));
    return s;
}

// ------- prep: f32->f16 conversions + bias pack + relay k/v proj + star zero -------
#define PREP_NV   1048576                // f16x8 items per tensor (8M elems / 8)
#define PREP_XE_B 8192
#define PREP_W_B  768
__global__ __launch_bounds__(256) void prep(
    const float* __restrict__ x, const float* __restrict__ e,
    const float* __restrict__ Wq, const float* __restrict__ Wk,
    const float* __restrict__ Wv, const float* __restrict__ Wo,
    const float* __restrict__ bq, const float* __restrict__ bk, const float* __restrict__ bv,
    const float* __restrict__ relay,
    _Float16* __restrict__ xh, _Float16* __restrict__ eh,
    _Float16* __restrict__ Wqkv, _Float16* __restrict__ Wof, float* __restrict__ bqkv,
    float* __restrict__ krvr, float* __restrict__ star)
{
    const int bid = blockIdx.x;
    if (bid < PREP_XE_B) {                   // x,e: 2*PREP_NV f16x8 items
        int j = bid * 256 + threadIdx.x;
        const float* src; _Float16* dst;
        if (j < PREP_NV) { src = x; dst = xh; } else { src = e; dst = eh; j -= PREP_NV; }
        const float* p = src + (size_t)j * 8;
        float4 a = *(const float4*)p, b = *(const float4*)(p + 4);
        f16x8 h = { (_Float16)a.x, (_Float16)a.y, (_Float16)a.z, (_Float16)a.w,
                    (_Float16)b.x, (_Float16)b.y, (_Float16)b.z, (_Float16)b.w };
        *(f16x8*)(dst + (size_t)j * 8) = h;
    } else if (bid < PREP_XE_B + PREP_W_B) { // weights: 196608 f16x4 items
        const int w = (bid - PREP_XE_B) * 256 + threadIdx.x;
        const int o = w * 4, r = o >> 9, c = o & 511;
        const float* W = (r < 512) ? Wq : (r < 1024 ? Wk : Wv);
        float4 v = *(const float4*)(W + (size_t)(r & 511) * 512 + c);
        *(f16x4*)(Wqkv + o) = f16x4{ (_Float16)v.x, (_Float16)v.y, (_Float16)v.z, (_Float16)v.w };
        if (o < 262144) {
            float4 u = *(const float4*)(Wo + o);
            *(f16x4*)(Wof + o) = f16x4{ (_Float16)u.x, (_Float16)u.y, (_Float16)u.z, (_Float16)u.w };
        }
        if (w < 1536) bqkv[w] = (w < 512) ? bq[w] : (w < 1024 ? bk[w - 512] : bv[w - 1024]);
    } else {                                 // relay k/v projection (fp32), wave-per-output
        const int o = ((bid - PREP_XE_B - PREP_W_B) << 2) + (threadIdx.x >> 6);   // 0..4095
        const int lane = threadIdx.x & 63;
        const int sel = o >> 11, rem = o & 2047, b = rem >> 9, j = rem & 511;
        const float* W = sel ? Wv : Wk;
        const float* wr = W + (size_t)j * 512 + lane * 8;
        const float* rp = relay + (size_t)b * 512 + lane * 8;
        float4 w0 = *(const float4*)wr,  w1 = *(const float4*)(wr + 4);
        float4 r0 = *(const float4*)rp,  r1 = *(const float4*)(rp + 4);
        float s = w0.x * r0.x + w0.y * r0.y + w0.z * r0.z + w0.w * r0.w
                + w1.x * r1.x + w1.y * r1.y + w1.z * r1.z + w1.w * r1.w;
        s = wred_sum(s);
        if (lane == 0) {
            krvr[o] = s + (sel ? bv[j] : bk[j]);
            if (o < 2048) star[o] = 0.f;
        }
    }
}

// ---------------- 2-phase 128x128 GEMM, 3-deep LDS ring (r9-proven) ----------
// C[M,cstride] <- A[M,512] * W[N,512]^T + bias. K=512 fixed (16 slices of 32).
// Depth-3 ring (48 KB, 3 blocks/CU), counted vmcnt 8/4/0, XOR bank swizzle
// (both-sides), setprio, LDS-bounce coalesced epilogue.
struct GemmP {
    const _Float16* A;      // [M,512]
    const _Float16* W;      // [N,512] (pre-offset)
    const float*    bias;   // pre-offset
    void*           C;
    int             cstride;
    int             ncols;  // col tiles = N/128
};

template<int OUT16>
__global__ __launch_bounds__(256) void gemm2p(GemmP g0, GemmP g1, int n0, int cpx)
{
    __shared__ __align__(16) char smem[49152];
    _Float16* lAb = (_Float16*)smem;             // 3 slices x 4096 elems (24 KB)
    _Float16* lBb = (_Float16*)(smem + 24576);   // 3 slices x 4096 elems

    const int bid = blockIdx.x;
    const int swz = (bid & 7) * cpx + (bid >> 3);        // bijective: grid%8==0
    const GemmP g = (swz < n0) ? g0 : g1;
    const int l  = (swz < n0) ? swz : swz - n0;
    const int mt = l / g.ncols, nt = l % g.ncols;
    const int row0 = mt * 128, col0 = nt * 128;

    const int tid = threadIdx.x;
    const int wave = tid >> 6, lane = tid & 63;
    const int wm = (wave >> 1) * 64, wn = (wave & 1) * 64;

    f32x4 acc[4][4];
#pragma unroll
    for (int i = 0; i < 4; ++i)
#pragma unroll
        for (int j = 0; j < 4; ++j) acc[i][j] = (f32x4)0.f;

    const int idx0 = tid, idx1 = 256 + tid;
    const int r0_ = idx0 >> 2, c0_ = ((idx0 & 3) ^ ((idx0 >> 3) & 3)) * 8;
    const int r1_ = idx1 >> 2, c1_ = ((idx1 & 3) ^ ((idx1 >> 3) & 3)) * 8;
    const int ldsb0 = (wave * 64) * 8;
    const int ldsb1 = (256 + wave * 64) * 8;

    auto stage = [&](int buf, int t) {
        const int k0 = t << 5;
        gload16(g.A + (size_t)(row0 + r0_) * 512 + k0 + c0_, lAb + buf * 4096 + ldsb0);
        gload16(g.A + (size_t)(row0 + r1_) * 512 + k0 + c1_, lAb + buf * 4096 + ldsb1);
        gload16(g.W + (size_t)(col0 + r0_) * 512 + k0 + c0_, lBb + buf * 4096 + ldsb0);
        gload16(g.W + (size_t)(col0 + r1_) * 512 + k0 + c1_, lBb + buf * 4096 + ldsb1);
    };
    stage(0, 0);
    stage(1, 1);
    stage(2, 2);          // 12 loads in flight

    const int rslot = ((lane >> 4) ^ ((lane >> 1) & 3)) * 8;
    const int arb = (wm + (lane & 15)) * 32 + rslot;
    const int brb = (wn + (lane & 15)) * 32 + rslot;

    int rs = 0;
#pragma unroll 1
    for (int t = 0; t < 16; ++t) {
        if (t < 14)       asm volatile("s_waitcnt vmcnt(8)" ::: "memory");
        else if (t == 14) asm volatile("s_waitcnt vmcnt(4)" ::: "memory");
        else              asm volatile("s_waitcnt vmcnt(0)" ::: "memory");
        __builtin_amdgcn_s_barrier();                 // tile t fully staged (all waves)
        f16x8 af[4], bfr[4];
#pragma unroll
        for (int i = 0; i < 4; ++i) af[i]  = *(const f16x8*)(lAb + rs * 4096 + arb + i * 512);
#pragma unroll
        for (int i = 0; i < 4; ++i) bfr[i] = *(const f16x8*)(lBb + rs * 4096 + brb + i * 512);
        __builtin_amdgcn_s_setprio(1);
#pragma unroll
        for (int mi = 0; mi < 4; ++mi)
#pragma unroll
            for (int ni = 0; ni < 4; ++ni)
                acc[mi][ni] = __builtin_amdgcn_mfma_f32_16x16x32_f16(
                    af[mi], bfr[ni], acc[mi][ni], 0, 0, 0);
        __builtin_amdgcn_s_setprio(0);
        asm volatile("s_waitcnt lgkmcnt(0)" ::: "memory");  // my reads of tile t done
        __builtin_amdgcn_s_barrier();                 // ALL waves done reading tile t
        if (t + 3 < 16) stage(rs, t + 3);             // slot t%3 freed -> tile t+3
        rs = (rs == 2) ? 0 : rs + 1;
    }
    // ring LDS dead -> reuse for epilogue bounce

    const int h = lane >> 4, c = lane & 15;
    if (OUT16) {
        _Float16* ep = (_Float16*)smem;               // [128][136] f16 (34816 B)
#pragma unroll
        for (int mi = 0; mi < 4; ++mi)
#pragma unroll
            for (int ni = 0; ni < 4; ++ni) {
                const float bb = g.bias[col0 + wn + ni * 16 + c];
#pragma unroll
                for (int r = 0; r < 4; ++r)
                    ep[(wm + mi * 16 + h * 4 + r) * 136 + wn + ni * 16 + c] =
                        (_Float16)(acc[mi][ni][r] + bb);
            }
        __syncthreads();
        const int rt = tid >> 4, ct = (tid & 15) * 8;
#pragma unroll
        for (int j = 0; j < 8; ++j) {
            const int row = j * 16 + rt;
            f16x8 v = *(const f16x8*)(ep + row * 136 + ct);
            *(f16x8*)((_Float16*)g.C + (size_t)(row0 + row) * g.cstride + col0 + ct) = v;
        }
    } else {
        float* ep = (float*)smem;                     // [64][132] f32 (33792 B) per pass
#pragma unroll
        for (int pass = 0; pass < 2; ++pass) {
            if ((wm == 0) == (pass == 0)) {           // waves owning these 64 rows write
#pragma unroll
                for (int mi = 0; mi < 4; ++mi)
#pragma unroll
                    for (int ni = 0; ni < 4; ++ni) {
                        const float bb = g.bias[col0 + wn + ni * 16 + c];
#pragma unroll
                        for (int r = 0; r < 4; ++r)
                            ep[(mi * 16 + h * 4 + r) * 132 + wn + ni * 16 + c] =
                                acc[mi][ni][r] + bb;
                    }
            }
            __syncthreads();
            const int rt = tid >> 5, ct4 = (tid & 31) * 4;
#pragma unroll
            for (int j = 0; j < 8; ++j) {
                const int row = j * 8 + rt;
                f32x4 v = *(const f32x4*)(ep + row * 132 + ct4);
                *(f32x4*)((float*)g.C + (size_t)(row0 + pass * 64 + row) * g.cstride + col0 + ct4) = v;
            }
            if (pass == 0) __syncthreads();           // reads done before pass-1 writes
        }
    }
}

// ---- tail: blocks [0,512) = out-projection gemm (f32 out); [512,1024) = star_proj ----
__global__ __launch_bounds__(256) void tail_fused(GemmP g,
    const float* __restrict__ star, const float* __restrict__ Wo,
    const float* __restrict__ bo, float* __restrict__ out1)
{
    __shared__ __align__(16) char smem[49152];
    const int bid = blockIdx.x;
    const int tid = threadIdx.x;
    const int lane = tid & 63;

    if (bid >= 512) {                 // ---- star_proj: wave per output ----
        const int o = ((bid - 512) << 2) + (tid >> 6);   // 0..2047
        const int b = o >> 9, j = o & 511;
        const float* sp = star + (size_t)b * 512 + lane * 8;
        const float* wr = Wo + (size_t)j * 512 + lane * 8;
        float4 w0 = *(const float4*)wr,  w1 = *(const float4*)(wr + 4);
        float4 s0 = *(const float4*)sp,  s1 = *(const float4*)(sp + 4);
        float s = w0.x * s0.x + w0.y * s0.y + w0.z * s0.z + w0.w * s0.w
                + w1.x * s1.x + w1.y * s1.y + w1.z * s1.z + w1.w * s1.w;
        s = wred_sum(s);
        if (lane == 0) out1[o] = s + bo[j];
        return;
    }

    // ---- out-projection gemm tile (r9 body, OUT16=0) ----
    _Float16* lAb = (_Float16*)smem;
    _Float16* lBb = (_Float16*)(smem + 24576);

    const int swz = (bid & 7) * 64 + (bid >> 3);         // bijective over 512
    const int mt = swz / g.ncols, nt = swz % g.ncols;
    const int row0 = mt * 128, col0 = nt * 128;

    const int wave = tid >> 6;
    const int wm = (wave >> 1) * 64, wn = (wave & 1) * 64;

    f32x4 acc[4][4];
#pragma unroll
    for (int i = 0; i < 4; ++i)
#pragma unroll
        for (int j = 0; j < 4; ++j) acc[i][j] = (f32x4)0.f;

    const int idx0 = tid, idx1 = 256 + tid;
    const int r0_ = idx0 >> 2, c0_ = ((idx0 & 3) ^ ((idx0 >> 3) & 3)) * 8;
    const int r1_ = idx1 >> 2, c1_ = ((idx1 & 3) ^ ((idx1 >> 3) & 3)) * 8;
    const int ldsb0 = (wave * 64) * 8;
    const int ldsb1 = (256 + wave * 64) * 8;

    auto stage = [&](int buf, int t) {
        const int k0 = t << 5;
        gload16(g.A + (size_t)(row0 + r0_) * 512 + k0 + c0_, lAb + buf * 4096 + ldsb0);
        gload16(g.A + (size_t)(row0 + r1_) * 512 + k0 + c1_, lAb + buf * 4096 + ldsb1);
        gload16(g.W + (size_t)(col0 + r0_) * 512 + k0 + c0_, lBb + buf * 4096 + ldsb0);
        gload16(g.W + (size_t)(col0 + r1_) * 512 + k0 + c1_, lBb + buf * 4096 + ldsb1);
    };
    stage(0, 0);
    stage(1, 1);
    stage(2, 2);

    const int rslot = ((lane >> 4) ^ ((lane >> 1) & 3)) * 8;
    const int arb = (wm + (lane & 15)) * 32 + rslot;
    const int brb = (wn + (lane & 15)) * 32 + rslot;

    int rs = 0;
#pragma unroll 1
    for (int t = 0; t < 16; ++t) {
        if (t < 14)       asm volatile("s_waitcnt vmcnt(8)" ::: "memory");
        else if (t == 14) asm volatile("s_waitcnt vmcnt(4)" ::: "memory");
        else              asm volatile("s_waitcnt vmcnt(0)" ::: "memory");
        __builtin_amdgcn_s_barrier();
        f16x8 af[4], bfr[4];
#pragma unroll
        for (int i = 0; i < 4; ++i) af[i]  = *(const f16x8*)(lAb + rs * 4096 + arb + i * 512);
#pragma unroll
        for (int i = 0; i < 4; ++i) bfr[i] = *(const f16x8*)(lBb + rs * 4096 + brb + i * 512);
        __builtin_amdgcn_s_setprio(1);
#pragma unroll
        for (int mi = 0; mi < 4; ++mi)
#pragma unroll
            for (int ni = 0; ni < 4; ++ni)
                acc[mi][ni] = __builtin_amdgcn_mfma_f32_16x16x32_f16(
                    af[mi], bfr[ni], acc[mi][ni], 0, 0, 0);
        __builtin_amdgcn_s_setprio(0);
        asm volatile("s_waitcnt lgkmcnt(0)" ::: "memory");
        __builtin_amdgcn_s_barrier();
        if (t + 3 < 16) stage(rs, t + 3);
        rs = (rs == 2) ? 0 : rs + 1;
    }

    const int h = lane >> 4, c = lane & 15;
    float* ep = (float*)smem;                     // [64][132] f32 per pass
#pragma unroll
    for (int pass = 0; pass < 2; ++pass) {
        if ((wm == 0) == (pass == 0)) {
#pragma unroll
            for (int mi = 0; mi < 4; ++mi)
#pragma unroll
                for (int ni = 0; ni < 4; ++ni) {
                    const float bb = g.bias[col0 + wn + ni * 16 + c];
#pragma unroll
                    for (int r = 0; r < 4; ++r)
                        ep[(mi * 16 + h * 4 + r) * 132 + wn + ni * 16 + c] =
                            acc[mi][ni][r] + bb;
                }
        }
        __syncthreads();
        const int rt = tid >> 5, ct4 = (tid & 31) * 4;
#pragma unroll
        for (int j = 0; j < 8; ++j) {
            const int row = j * 8 + rt;
            f32x4 v = *(const f32x4*)(ep + row * 132 + ct4);
            *(f32x4*)((float*)g.C + (size_t)(row0 + pass * 64 + row) * g.cstride + col0 + ct4) = v;
        }
        if (pass == 0) __syncthreads();
    }
}

// ------- ring attention (one wave per (l,b)) + fused star logits -------
__global__ __launch_bounds__(256) void ring_attn(
    const _Float16* __restrict__ qkv,    // [M,1536] q|k|v
    const _Float16* __restrict__ ekv,    // [M,1024] ke|ve
    const float* __restrict__ krvr,      // [2][B][512]
    const float* __restrict__ relay,     // [B,512]
    _Float16* __restrict__ ring,         // [M,512]
    float* __restrict__ slog)            // [B,SLS]
{
    const int wid = (blockIdx.x << 2) + (threadIdx.x >> 6);   // row r = l*B+b
    const int lane = threadIdx.x & 63;
    const int r = wid, b = r & 3, l = r >> 2;
    const int d0 = lane << 3;

    float q[8], rl[8];
    {
        f16x8 t = *(const f16x8*)(qkv + (size_t)r * 1536 + d0);
#pragma unroll
        for (int i = 0; i < 8; ++i) q[i] = (float)t[i];
        const float* rp = relay + (size_t)b * 512 + d0;
        float4 a = *(const float4*)rp, c = *(const float4*)(rp + 4);
        rl[0] = a.x; rl[1] = a.y; rl[2] = a.z; rl[3] = a.w;
        rl[4] = c.x; rl[5] = c.y; rl[6] = c.z; rl[7] = c.w;
    }
    const bool has0 = (l > 0), has2 = (l < L_SEQ - 1);

    auto dotk = [&](const _Float16* kp) -> float {
        f16x8 t = *(const f16x8*)(kp + d0);
        float s = 0.f;
#pragma unroll
        for (int i = 0; i < 8; ++i) s += q[i] * (float)t[i];
        return wred_sum(s);
    };

    float lg[5];
    lg[0] = has0 ? dotk(qkv + (size_t)(r - 4) * 1536 + 512) : 0.f;  // zero key -> logit 0
    lg[2] = has2 ? dotk(qkv + (size_t)(r + 4) * 1536 + 512) : 0.f;
    lg[3] = dotk(ekv + (size_t)r * 1024);
    {   // self k row: ring logit + star logit (relay . k)
        f16x8 t = *(const f16x8*)(qkv + (size_t)r * 1536 + 512 + d0);
        float s1 = 0.f, s2 = 0.f;
#pragma unroll
        for (int i = 0; i < 8; ++i) { float kf = (float)t[i]; s1 += q[i] * kf; s2 += rl[i] * kf; }
#pragma unroll
        for (int o = 32; o; o >>= 1) { s1 += __shfl_xor(s1, o); s2 += __shfl_xor(s2, o); }
        lg[1] = s1;
        if (lane == 0) slog[(size_t)b * SLS + l] = s2 * SCALE;
    }
    {   // relay key
        const float* kp = krvr + (size_t)b * 512 + d0;
        float s = 0.f;
#pragma unroll
        for (int i = 0; i < 8; ++i) s += q[i] * kp[i];
        lg[4] = wred_sum(s);
    }

    float li[5], m = -1e30f;
#pragma unroll
    for (int w = 0; w < 5; ++w) { li[w] = lg[w] * SCALE; m = fmaxf(m, li[w]); }
    float ew[5], Z = 0.f;
#pragma unroll
    for (int w = 0; w < 5; ++w) { ew[w] = expf(li[w] - m); Z += ew[w]; }
    const float inv = 1.f / Z;

    float o8[8] = {0, 0, 0, 0, 0, 0, 0, 0};
    auto addv = [&](const _Float16* vp, float a) {
        f16x8 t = *(const f16x8*)(vp + d0);
#pragma unroll
        for (int i = 0; i < 8; ++i) o8[i] += a * (float)t[i];
    };
    if (has0) addv(qkv + (size_t)(r - 4) * 1536 + 1024, ew[0] * inv);
    addv(qkv + (size_t)r * 1536 + 1024, ew[1] * inv);
    if (has2) addv(qkv + (size_t)(r + 4) * 1536 + 1024, ew[2] * inv);
    addv(ekv + (size_t)r * 1024 + 512, ew[3] * inv);
    {
        const float* vp = krvr + 2048 + (size_t)b * 512 + d0;
        const float a = ew[4] * inv;
#pragma unroll
        for (int i = 0; i < 8; ++i) o8[i] += a * vp[i];
    }
    f16x8 res;
#pragma unroll
    for (int i = 0; i < 8; ++i) res[i] = (_Float16)o8[i];
    *(f16x8*)(ring + (size_t)r * 512 + d0) = res;
}

// ---------------- star softmax: one 1024-thread block per batch ----------------
__global__ __launch_bounds__(1024) void star_softmax(
    const float* __restrict__ relay, const float* __restrict__ krvr,
    float* __restrict__ slog)
{
    const int b = blockIdx.x, t = threadIdx.x, lane = t & 63, w = t >> 6;
    __shared__ float red[16];
    __shared__ float bc[2];
    float* sl = slog + (size_t)b * SLS;

    float p = 0.f;
    if (t < 512) p = relay[(size_t)b * 512 + t] * krvr[(size_t)b * 512 + t];
    p = wred_sum(p);
    if (lane == 0) red[w] = p;
    __syncthreads();
    if (t == 0) { float s = 0.f; for (int i = 0; i < 16; ++i) s += red[i]; bc[0] = s * SCALE; }
    __syncthreads();
    const float selfl = bc[0];
    __syncthreads();

    float v[4];
#pragma unroll
    for (int i = 0; i < 4; ++i) v[i] = sl[t + i * 1024];

    float m = selfl;
#pragma unroll
    for (int i = 0; i < 4; ++i) m = fmaxf(m, v[i]);
    m = wred_max(m);
    if (lane == 0) red[w] = m;
    __syncthreads();
    if (t == 0) { float mm = red[0]; for (int i = 1; i < 16; ++i) mm = fmaxf(mm, red[i]); bc[1] = mm; }
    __syncthreads();
    m = bc[1];

    float ev[4], z = (t == 0) ? expf(selfl - m) : 0.f;
#pragma unroll
    for (int i = 0; i < 4; ++i) { ev[i] = expf(v[i] - m); z += ev[i]; }
    z = wred_sum(z);
    if (lane == 0) red[w] = z;
    __syncthreads();
    if (t == 0) { float s = 0.f; for (int i = 0; i < 16; ++i) s += red[i]; bc[0] = 1.f / s; }
    __syncthreads();
    const float inv = bc[0];

#pragma unroll
    for (int i = 0; i < 4; ++i) sl[t + i * 1024] = ev[i] * inv;
    if (t == 0) sl[SLS - 1] = expf(selfl - m) * inv;
}

// ------- star weighted V-sum: wave per (chunk,b), 256 blocks x 16 n -------
__global__ __launch_bounds__(256) void star_out(
    const float* __restrict__ slog, const _Float16* __restrict__ qkv,
    const float* __restrict__ krvr, float* __restrict__ star)
{
    const int b = threadIdx.x >> 6, lane = threadIdx.x & 63;
    const int chunk = blockIdx.x;                 // 256 chunks x 16 n each
    const int d0 = lane << 3;
    const float* al = slog + (size_t)b * SLS;
    float acc[8] = {0, 0, 0, 0, 0, 0, 0, 0};
#pragma unroll 4
    for (int i = 0; i < 16; ++i) {
        const int n = chunk * 16 + i;
        const float a = al[n];
        f16x8 v = *(const f16x8*)(qkv + (size_t)(n * 4 + b) * 1536 + 1024 + d0);
#pragma unroll
        for (int j = 0; j < 8; ++j) acc[j] += a * (float)v[j];
    }
    if (chunk == 255) {
        const float a = al[SLS - 1];
        const float* vr = krvr + 2048 + (size_t)b * 512 + d0;
#pragma unroll
        for (int j = 0; j < 8; ++j) acc[j] += a * vr[j];
    }
#pragma unroll
    for (int j = 0; j < 8; ++j) atomicAdd(&star[(size_t)b * 512 + d0 + j], acc[j]);
}

// ---------------- host launch ----------------
extern "C" void kernel_launch(void* const* d_in, const int* in_sizes, int n_in,
                              void* d_out, int out_size, void* d_ws, size_t ws_size,
                              hipStream_t stream) {
    const float* x     = (const float*)d_in[0];
    const float* e     = (const float*)d_in[1];
    const float* relay = (const float*)d_in[2];
    const float* Wq    = (const float*)d_in[3];
    const float* bq    = (const float*)d_in[4];
    const float* Wk    = (const float*)d_in[5];
    const float* bk    = (const float*)d_in[6];
    const float* Wv    = (const float*)d_in[7];
    const float* bv    = (const float*)d_in[8];
    const float* Wo    = (const float*)d_in[9];
    const float* bo    = (const float*)d_in[10];
    float* out = (float*)d_out;

    size_t off = 0;
    auto alloc = [&](size_t bytes) {
        void* p = (char*)d_ws + off;
        off += (bytes + 255) & ~(size_t)255;
        return p;
    };
    _Float16* Wqkv = (_Float16*)alloc((size_t)1536 * 512 * 2);
    _Float16* Wof  = (_Float16*)alloc((size_t)512 * 512 * 2);
    float*    bqkv = (float*)   alloc(1536 * 4);
    _Float16* xh   = (_Float16*)alloc((size_t)M_ROWS * 512 * 2);
    _Float16* eh   = (_Float16*)alloc((size_t)M_ROWS * 512 * 2);
    _Float16* qkv  = (_Float16*)alloc((size_t)M_ROWS * 1536 * 2);
    _Float16* ekv  = (_Float16*)alloc((size_t)M_ROWS * 1024 * 2);
    float*    krvr = (float*)   alloc(2 * 4 * 512 * 4);
    float*    slog = (float*)   alloc((size_t)4 * SLS * 4);
    float*    star = (float*)   alloc(4 * 512 * 4);
    _Float16* ringb = xh;   // alias: xh is dead after the fused qkv/ekv GEMM

    prep<<<PREP_XE_B + PREP_W_B + 1024, 256, 0, stream>>>(
        x, e, Wq, Wk, Wv, Wo, bq, bk, bv, relay,
        xh, eh, Wqkv, Wof, bqkv, krvr, star);

    // fused qkv (128x12=1536 tiles) + ekv (128x8=1024 tiles): 2560 blocks
    GemmP gq { xh, Wqkv,                     bqkv,       qkv, 1536, 12 };
    GemmP ge { eh, Wqkv + (size_t)512 * 512, bqkv + 512, ekv, 1024,  8 };
    gemm2p<1><<<2560, 256, 0, stream>>>(gq, ge, 1536, 320);

    ring_attn<<<M_ROWS / 4, 256, 0, stream>>>(qkv, ekv, krvr, relay, ringb, slog);

    star_softmax<<<4, 1024, 0, stream>>>(relay, krvr, slog);
    star_out<<<256, 256, 0, stream>>>(slog, qkv, krvr, star);

    // merged tail: out-projection (512 gemm tiles) + star_proj (512 blocks)
    GemmP go { ringb, Wof, bo, out, 512, 4 };
    tail_fused<<<1024, 256, 0, stream>>>(go, star, Wo, bo, out + (size_t)M_ROWS * 512);
}

// Round 13
// 151.118 us; speedup vs baseline: 1.3156x; 1.3094x over previous
//
#include <hip/hip_runtime.h>
#include <hip/hip_fp16.h>

#define L_SEQ 4096
#define BATCH 4
#define DIM 512
#define M_ROWS (L_SEQ * BATCH)          // 16384
#define SCALE 0.04419417382415922f      // 1/sqrt(512)
#define SLS 4097                         // star logits per batch (L+1)

typedef __attribute__((ext_vector_type(4))) float f32x4;
typedef __attribute__((ext_vector_type(8))) _Float16 f16x8;
typedef __attribute__((ext_vector_type(4))) _Float16 f16x4;

__device__ inline void gload16(const void* g, void* l) {
    __builtin_amdgcn_global_load_lds(
        (const __attribute__((address_space(1))) void*)g,
        (__attribute__((address_space(3))) void*)l, 16, 0, 0);
}

__device__ inline float wred_sum(float s) {
#pragma unroll
    for (int o = 32; o; o >>= 1) s += __shfl_xor(s, o);
    return s;
}
__device__ inline float wred_max(float s) {
#pragma unroll
    for (int o = 32; o; o >>= 1) s = fmaxf(s, __shfl_xor(s, o));
    return s;
}

// ------- prep: f32->f16 conversions + bias pack + relay k/v proj + star zero -------
#define PREP_NV   1048576                // f16x8 items per tensor (8M elems / 8)
#define PREP_XE_B 8192
#define PREP_W_B  768
__global__ __launch_bounds__(256) void prep(
    const float* __restrict__ x, const float* __restrict__ e,
    const float* __restrict__ Wq, const float* __restrict__ Wk,
    const float* __restrict__ Wv, const float* __restrict__ Wo,
    const float* __restrict__ bq, const float* __restrict__ bk, const float* __restrict__ bv,
    const float* __restrict__ relay,
    _Float16* __restrict__ xh, _Float16* __restrict__ eh,
    _Float16* __restrict__ Wqkv, _Float16* __restrict__ Wof, float* __restrict__ bqkv,
    float* __restrict__ krvr, float* __restrict__ star)
{
    const int bid = blockIdx.x;
    if (bid < PREP_XE_B) {                   // x,e: 2*PREP_NV f16x8 items
        int j = bid * 256 + threadIdx.x;
        const float* src; _Float16* dst;
        if (j < PREP_NV) { src = x; dst = xh; } else { src = e; dst = eh; j -= PREP_NV; }
        const float* p = src + (size_t)j * 8;
        float4 a = *(const float4*)p, b = *(const float4*)(p + 4);
        f16x8 h = { (_Float16)a.x, (_Float16)a.y, (_Float16)a.z, (_Float16)a.w,
                    (_Float16)b.x, (_Float16)b.y, (_Float16)b.z, (_Float16)b.w };
        *(f16x8*)(dst + (size_t)j * 8) = h;
    } else if (bid < PREP_XE_B + PREP_W_B) { // weights: 196608 f16x4 items
        const int w = (bid - PREP_XE_B) * 256 + threadIdx.x;
        const int o = w * 4, r = o >> 9, c = o & 511;
        const float* W = (r < 512) ? Wq : (r < 1024 ? Wk : Wv);
        float4 v = *(const float4*)(W + (size_t)(r & 511) * 512 + c);
        *(f16x4*)(Wqkv + o) = f16x4{ (_Float16)v.x, (_Float16)v.y, (_Float16)v.z, (_Float16)v.w };
        if (o < 262144) {
            float4 u = *(const float4*)(Wo + o);
            *(f16x4*)(Wof + o) = f16x4{ (_Float16)u.x, (_Float16)u.y, (_Float16)u.z, (_Float16)u.w };
        }
        if (w < 1536) bqkv[w] = (w < 512) ? bq[w] : (w < 1024 ? bk[w - 512] : bv[w - 1024]);
    } else {                                 // relay k/v projection (fp32), wave-per-output
        const int o = ((bid - PREP_XE_B - PREP_W_B) << 2) + (threadIdx.x >> 6);   // 0..4095
        const int lane = threadIdx.x & 63;
        const int sel = o >> 11, rem = o & 2047, b = rem >> 9, j = rem & 511;
        const float* W = sel ? Wv : Wk;
        const float* wr = W + (size_t)j * 512 + lane * 8;
        const float* rp = relay + (size_t)b * 512 + lane * 8;
        float4 w0 = *(const float4*)wr,  w1 = *(const float4*)(wr + 4);
        float4 r0 = *(const float4*)rp,  r1 = *(const float4*)(rp + 4);
        float s = w0.x * r0.x + w0.y * r0.y + w0.z * r0.z + w0.w * r0.w
                + w1.x * r1.x + w1.y * r1.y + w1.z * r1.z + w1.w * r1.w;
        s = wred_sum(s);
        if (lane == 0) {
            krvr[o] = s + (sel ? bv[j] : bk[j]);
            if (o < 2048) star[o] = 0.f;
        }
    }
}

// ---------------- 2-phase 128x128 GEMM, 3-deep LDS ring (r9-proven) ----------
struct GemmP {
    const _Float16* A;      // [M,512]
    const _Float16* W;      // [N,512] (pre-offset)
    const float*    bias;   // pre-offset
    void*           C;
    int             cstride;
    int             ncols;  // col tiles = N/128
};

template<int OUT16>
__global__ __launch_bounds__(256) void gemm2p(GemmP g0, GemmP g1, int n0, int cpx)
{
    __shared__ __align__(16) char smem[49152];
    _Float16* lAb = (_Float16*)smem;             // 3 slices x 4096 elems (24 KB)
    _Float16* lBb = (_Float16*)(smem + 24576);   // 3 slices x 4096 elems

    const int bid = blockIdx.x;
    const int swz = (bid & 7) * cpx + (bid >> 3);        // bijective: grid%8==0
    const GemmP g = (swz < n0) ? g0 : g1;
    const int l  = (swz < n0) ? swz : swz - n0;
    const int mt = l / g.ncols, nt = l % g.ncols;
    const int row0 = mt * 128, col0 = nt * 128;

    const int tid = threadIdx.x;
    const int wave = tid >> 6, lane = tid & 63;
    const int wm = (wave >> 1) * 64, wn = (wave & 1) * 64;

    f32x4 acc[4][4];
#pragma unroll
    for (int i = 0; i < 4; ++i)
#pragma unroll
        for (int j = 0; j < 4; ++j) acc[i][j] = (f32x4)0.f;

    const int idx0 = tid, idx1 = 256 + tid;
    const int r0_ = idx0 >> 2, c0_ = ((idx0 & 3) ^ ((idx0 >> 3) & 3)) * 8;
    const int r1_ = idx1 >> 2, c1_ = ((idx1 & 3) ^ ((idx1 >> 3) & 3)) * 8;
    const int ldsb0 = (wave * 64) * 8;
    const int ldsb1 = (256 + wave * 64) * 8;

    auto stage = [&](int buf, int t) {
        const int k0 = t << 5;
        gload16(g.A + (size_t)(row0 + r0_) * 512 + k0 + c0_, lAb + buf * 4096 + ldsb0);
        gload16(g.A + (size_t)(row0 + r1_) * 512 + k0 + c1_, lAb + buf * 4096 + ldsb1);
        gload16(g.W + (size_t)(col0 + r0_) * 512 + k0 + c0_, lBb + buf * 4096 + ldsb0);
        gload16(g.W + (size_t)(col0 + r1_) * 512 + k0 + c1_, lBb + buf * 4096 + ldsb1);
    };
    stage(0, 0);
    stage(1, 1);
    stage(2, 2);          // 12 loads in flight

    const int rslot = ((lane >> 4) ^ ((lane >> 1) & 3)) * 8;
    const int arb = (wm + (lane & 15)) * 32 + rslot;
    const int brb = (wn + (lane & 15)) * 32 + rslot;

    int rs = 0;
#pragma unroll 1
    for (int t = 0; t < 16; ++t) {
        if (t < 14)       asm volatile("s_waitcnt vmcnt(8)" ::: "memory");
        else if (t == 14) asm volatile("s_waitcnt vmcnt(4)" ::: "memory");
        else              asm volatile("s_waitcnt vmcnt(0)" ::: "memory");
        __builtin_amdgcn_s_barrier();                 // tile t fully staged (all waves)
        f16x8 af[4], bfr[4];
#pragma unroll
        for (int i = 0; i < 4; ++i) af[i]  = *(const f16x8*)(lAb + rs * 4096 + arb + i * 512);
#pragma unroll
        for (int i = 0; i < 4; ++i) bfr[i] = *(const f16x8*)(lBb + rs * 4096 + brb + i * 512);
        __builtin_amdgcn_s_setprio(1);
#pragma unroll
        for (int mi = 0; mi < 4; ++mi)
#pragma unroll
            for (int ni = 0; ni < 4; ++ni)
                acc[mi][ni] = __builtin_amdgcn_mfma_f32_16x16x32_f16(
                    af[mi], bfr[ni], acc[mi][ni], 0, 0, 0);
        __builtin_amdgcn_s_setprio(0);
        asm volatile("s_waitcnt lgkmcnt(0)" ::: "memory");  // my reads of tile t done
        __builtin_amdgcn_s_barrier();                 // ALL waves done reading tile t
        if (t + 3 < 16) stage(rs, t + 3);             // slot t%3 freed -> tile t+3
        rs = (rs == 2) ? 0 : rs + 1;
    }
    // ring LDS dead -> reuse for epilogue bounce

    const int h = lane >> 4, c = lane & 15;
    if (OUT16) {
        _Float16* ep = (_Float16*)smem;               // [128][136] f16 (34816 B)
#pragma unroll
        for (int mi = 0; mi < 4; ++mi)
#pragma unroll
            for (int ni = 0; ni < 4; ++ni) {
                const float bb = g.bias[col0 + wn + ni * 16 + c];
#pragma unroll
                for (int r = 0; r < 4; ++r)
                    ep[(wm + mi * 16 + h * 4 + r) * 136 + wn + ni * 16 + c] =
                        (_Float16)(acc[mi][ni][r] + bb);
            }
        __syncthreads();
        const int rt = tid >> 4, ct = (tid & 15) * 8;
#pragma unroll
        for (int j = 0; j < 8; ++j) {
            const int row = j * 16 + rt;
            f16x8 v = *(const f16x8*)(ep + row * 136 + ct);
            *(f16x8*)((_Float16*)g.C + (size_t)(row0 + row) * g.cstride + col0 + ct) = v;
        }
    } else {
        float* ep = (float*)smem;                     // [64][132] f32 (33792 B) per pass
#pragma unroll
        for (int pass = 0; pass < 2; ++pass) {
            if ((wm == 0) == (pass == 0)) {           // waves owning these 64 rows write
#pragma unroll
                for (int mi = 0; mi < 4; ++mi)
#pragma unroll
                    for (int ni = 0; ni < 4; ++ni) {
                        const float bb = g.bias[col0 + wn + ni * 16 + c];
#pragma unroll
                        for (int r = 0; r < 4; ++r)
                            ep[(mi * 16 + h * 4 + r) * 132 + wn + ni * 16 + c] =
                                acc[mi][ni][r] + bb;
                    }
            }
            __syncthreads();
            const int rt = tid >> 5, ct4 = (tid & 31) * 4;
#pragma unroll
            for (int j = 0; j < 8; ++j) {
                const int row = j * 8 + rt;
                f32x4 v = *(const f32x4*)(ep + row * 132 + ct4);
                *(f32x4*)((float*)g.C + (size_t)(row0 + pass * 64 + row) * g.cstride + col0 + ct4) = v;
            }
            if (pass == 0) __syncthreads();           // reads done before pass-1 writes
        }
    }
}

// ---- tail: blocks [0,512) = out-projection gemm (f32 out); [512,1024) = star_proj ----
__global__ __launch_bounds__(256) void tail_fused(GemmP g,
    const float* __restrict__ star, const float* __restrict__ Wo,
    const float* __restrict__ bo, float* __restrict__ out1)
{
    __shared__ __align__(16) char smem[49152];
    const int bid = blockIdx.x;
    const int tid = threadIdx.x;
    const int lane = tid & 63;

    if (bid >= 512) {                 // ---- star_proj: wave per output ----
        const int o = ((bid - 512) << 2) + (tid >> 6);   // 0..2047
        const int b = o >> 9, j = o & 511;
        const float* sp = star + (size_t)b * 512 + lane * 8;
        const float* wr = Wo + (size_t)j * 512 + lane * 8;
        float4 w0 = *(const float4*)wr,  w1 = *(const float4*)(wr + 4);
        float4 s0 = *(const float4*)sp,  s1 = *(const float4*)(sp + 4);
        float s = w0.x * s0.x + w0.y * s0.y + w0.z * s0.z + w0.w * s0.w
                + w1.x * s1.x + w1.y * s1.y + w1.z * s1.z + w1.w * s1.w;
        s = wred_sum(s);
        if (lane == 0) out1[o] = s + bo[j];
        return;
    }

    // ---- out-projection gemm tile (r9 body, OUT16=0) ----
    _Float16* lAb = (_Float16*)smem;
    _Float16* lBb = (_Float16*)(smem + 24576);

    const int swz = (bid & 7) * 64 + (bid >> 3);         // bijective over 512
    const int mt = swz / g.ncols, nt = swz % g.ncols;
    const int row0 = mt * 128, col0 = nt * 128;

    const int wave = tid >> 6;
    const int wm = (wave >> 1) * 64, wn = (wave & 1) * 64;

    f32x4 acc[4][4];
#pragma unroll
    for (int i = 0; i < 4; ++i)
#pragma unroll
        for (int j = 0; j < 4; ++j) acc[i][j] = (f32x4)0.f;

    const int idx0 = tid, idx1 = 256 + tid;
    const int r0_ = idx0 >> 2, c0_ = ((idx0 & 3) ^ ((idx0 >> 3) & 3)) * 8;
    const int r1_ = idx1 >> 2, c1_ = ((idx1 & 3) ^ ((idx1 >> 3) & 3)) * 8;
    const int ldsb0 = (wave * 64) * 8;
    const int ldsb1 = (256 + wave * 64) * 8;

    auto stage = [&](int buf, int t) {
        const int k0 = t << 5;
        gload16(g.A + (size_t)(row0 + r0_) * 512 + k0 + c0_, lAb + buf * 4096 + ldsb0);
        gload16(g.A + (size_t)(row0 + r1_) * 512 + k0 + c1_, lAb + buf * 4096 + ldsb1);
        gload16(g.W + (size_t)(col0 + r0_) * 512 + k0 + c0_, lBb + buf * 4096 + ldsb0);
        gload16(g.W + (size_t)(col0 + r1_) * 512 + k0 + c1_, lBb + buf * 4096 + ldsb1);
    };
    stage(0, 0);
    stage(1, 1);
    stage(2, 2);

    const int rslot = ((lane >> 4) ^ ((lane >> 1) & 3)) * 8;
    const int arb = (wm + (lane & 15)) * 32 + rslot;
    const int brb = (wn + (lane & 15)) * 32 + rslot;

    int rs = 0;
#pragma unroll 1
    for (int t = 0; t < 16; ++t) {
        if (t < 14)       asm volatile("s_waitcnt vmcnt(8)" ::: "memory");
        else if (t == 14) asm volatile("s_waitcnt vmcnt(4)" ::: "memory");
        else              asm volatile("s_waitcnt vmcnt(0)" ::: "memory");
        __builtin_amdgcn_s_barrier();
        f16x8 af[4], bfr[4];
#pragma unroll
        for (int i = 0; i < 4; ++i) af[i]  = *(const f16x8*)(lAb + rs * 4096 + arb + i * 512);
#pragma unroll
        for (int i = 0; i < 4; ++i) bfr[i] = *(const f16x8*)(lBb + rs * 4096 + brb + i * 512);
        __builtin_amdgcn_s_setprio(1);
#pragma unroll
        for (int mi = 0; mi < 4; ++mi)
#pragma unroll
            for (int ni = 0; ni < 4; ++ni)
                acc[mi][ni] = __builtin_amdgcn_mfma_f32_16x16x32_f16(
                    af[mi], bfr[ni], acc[mi][ni], 0, 0, 0);
        __builtin_amdgcn_s_setprio(0);
        asm volatile("s_waitcnt lgkmcnt(0)" ::: "memory");
        __builtin_amdgcn_s_barrier();
        if (t + 3 < 16) stage(rs, t + 3);
        rs = (rs == 2) ? 0 : rs + 1;
    }

    const int h = lane >> 4, c = lane & 15;
    float* ep = (float*)smem;                     // [64][132] f32 per pass
#pragma unroll
    for (int pass = 0; pass < 2; ++pass) {
        if ((wm == 0) == (pass == 0)) {
#pragma unroll
            for (int mi = 0; mi < 4; ++mi)
#pragma unroll
                for (int ni = 0; ni < 4; ++ni) {
                    const float bb = g.bias[col0 + wn + ni * 16 + c];
#pragma unroll
                    for (int r = 0; r < 4; ++r)
                        ep[(mi * 16 + h * 4 + r) * 132 + wn + ni * 16 + c] =
                            acc[mi][ni][r] + bb;
                }
        }
        __syncthreads();
        const int rt = tid >> 5, ct4 = (tid & 31) * 4;
#pragma unroll
        for (int j = 0; j < 8; ++j) {
            const int row = j * 8 + rt;
            f32x4 v = *(const f32x4*)(ep + row * 132 + ct4);
            *(f32x4*)((float*)g.C + (size_t)(row0 + pass * 64 + row) * g.cstride + col0 + ct4) = v;
        }
        if (pass == 0) __syncthreads();
    }
}

// ------- ring attention (one wave per (l,b)) + fused star logits -------
__global__ __launch_bounds__(256) void ring_attn(
    const _Float16* __restrict__ qkv,    // [M,1536] q|k|v
    const _Float16* __restrict__ ekv,    // [M,1024] ke|ve
    const float* __restrict__ krvr,      // [2][B][512]
    const float* __restrict__ relay,     // [B,512]
    _Float16* __restrict__ ring,         // [M,512]
    float* __restrict__ slog)            // [B,SLS]
{
    const int wid = (blockIdx.x << 2) + (threadIdx.x >> 6);   // row r = l*B+b
    const int lane = threadIdx.x & 63;
    const int r = wid, b = r & 3, l = r >> 2;
    const int d0 = lane << 3;

    float q[8], rl[8];
    {
        f16x8 t = *(const f16x8*)(qkv + (size_t)r * 1536 + d0);
#pragma unroll
        for (int i = 0; i < 8; ++i) q[i] = (float)t[i];
        const float* rp = relay + (size_t)b * 512 + d0;
        float4 a = *(const float4*)rp, c = *(const float4*)(rp + 4);
        rl[0] = a.x; rl[1] = a.y; rl[2] = a.z; rl[3] = a.w;
        rl[4] = c.x; rl[5] = c.y; rl[6] = c.z; rl[7] = c.w;
    }
    const bool has0 = (l > 0), has2 = (l < L_SEQ - 1);

    auto dotk = [&](const _Float16* kp) -> float {
        f16x8 t = *(const f16x8*)(kp + d0);
        float s = 0.f;
#pragma unroll
        for (int i = 0; i < 8; ++i) s += q[i] * (float)t[i];
        return wred_sum(s);
    };

    float lg[5];
    lg[0] = has0 ? dotk(qkv + (size_t)(r - 4) * 1536 + 512) : 0.f;  // zero key -> logit 0
    lg[2] = has2 ? dotk(qkv + (size_t)(r + 4) * 1536 + 512) : 0.f;
    lg[3] = dotk(ekv + (size_t)r * 1024);
    {   // self k row: ring logit + star logit (relay . k)
        f16x8 t = *(const f16x8*)(qkv + (size_t)r * 1536 + 512 + d0);
        float s1 = 0.f, s2 = 0.f;
#pragma unroll
        for (int i = 0; i < 8; ++i) { float kf = (float)t[i]; s1 += q[i] * kf; s2 += rl[i] * kf; }
#pragma unroll
        for (int o = 32; o; o >>= 1) { s1 += __shfl_xor(s1, o); s2 += __shfl_xor(s2, o); }
        lg[1] = s1;
        if (lane == 0) slog[(size_t)b * SLS + l] = s2 * SCALE;
    }
    {   // relay key
        const float* kp = krvr + (size_t)b * 512 + d0;
        float s = 0.f;
#pragma unroll
        for (int i = 0; i < 8; ++i) s += q[i] * kp[i];
        lg[4] = wred_sum(s);
    }

    float li[5], m = -1e30f;
#pragma unroll
    for (int w = 0; w < 5; ++w) { li[w] = lg[w] * SCALE; m = fmaxf(m, li[w]); }
    float ew[5], Z = 0.f;
#pragma unroll
    for (int w = 0; w < 5; ++w) { ew[w] = expf(li[w] - m); Z += ew[w]; }
    const float inv = 1.f / Z;

    float o8[8] = {0, 0, 0, 0, 0, 0, 0, 0};
    auto addv = [&](const _Float16* vp, float a) {
        f16x8 t = *(const f16x8*)(vp + d0);
#pragma unroll
        for (int i = 0; i < 8; ++i) o8[i] += a * (float)t[i];
    };
    if (has0) addv(qkv + (size_t)(r - 4) * 1536 + 1024, ew[0] * inv);
    addv(qkv + (size_t)r * 1536 + 1024, ew[1] * inv);
    if (has2) addv(qkv + (size_t)(r + 4) * 1536 + 1024, ew[2] * inv);
    addv(ekv + (size_t)r * 1024 + 512, ew[3] * inv);
    {
        const float* vp = krvr + 2048 + (size_t)b * 512 + d0;
        const float a = ew[4] * inv;
#pragma unroll
        for (int i = 0; i < 8; ++i) o8[i] += a * vp[i];
    }
    f16x8 res;
#pragma unroll
    for (int i = 0; i < 8; ++i) res[i] = (_Float16)o8[i];
    *(f16x8*)(ring + (size_t)r * 512 + d0) = res;
}

// ---------------- star softmax: one 1024-thread block per batch ----------------
__global__ __launch_bounds__(1024) void star_softmax(
    const float* __restrict__ relay, const float* __restrict__ krvr,
    float* __restrict__ slog)
{
    const int b = blockIdx.x, t = threadIdx.x, lane = t & 63, w = t >> 6;
    __shared__ float red[16];
    __shared__ float bc[2];
    float* sl = slog + (size_t)b * SLS;

    float p = 0.f;
    if (t < 512) p = relay[(size_t)b * 512 + t] * krvr[(size_t)b * 512 + t];
    p = wred_sum(p);
    if (lane == 0) red[w] = p;
    __syncthreads();
    if (t == 0) { float s = 0.f; for (int i = 0; i < 16; ++i) s += red[i]; bc[0] = s * SCALE; }
    __syncthreads();
    const float selfl = bc[0];
    __syncthreads();

    float v[4];
#pragma unroll
    for (int i = 0; i < 4; ++i) v[i] = sl[t + i * 1024];

    float m = selfl;
#pragma unroll
    for (int i = 0; i < 4; ++i) m = fmaxf(m, v[i]);
    m = wred_max(m);
    if (lane == 0) red[w] = m;
    __syncthreads();
    if (t == 0) { float mm = red[0]; for (int i = 1; i < 16; ++i) mm = fmaxf(mm, red[i]); bc[1] = mm; }
    __syncthreads();
    m = bc[1];

    float ev[4], z = (t == 0) ? expf(selfl - m) : 0.f;
#pragma unroll
    for (int i = 0; i < 4; ++i) { ev[i] = expf(v[i] - m); z += ev[i]; }
    z = wred_sum(z);
    if (lane == 0) red[w] = z;
    __syncthreads();
    if (t == 0) { float s = 0.f; for (int i = 0; i < 16; ++i) s += red[i]; bc[0] = 1.f / s; }
    __syncthreads();
    const float inv = bc[0];

#pragma unroll
    for (int i = 0; i < 4; ++i) sl[t + i * 1024] = ev[i] * inv;
    if (t == 0) sl[SLS - 1] = expf(selfl - m) * inv;
}

// ------- star weighted V-sum: wave per (chunk,b), 64 blocks x 64 n (r9-proven) -------
__global__ __launch_bounds__(256) void star_out(
    const float* __restrict__ slog, const _Float16* __restrict__ qkv,
    const float* __restrict__ krvr, float* __restrict__ star)
{
    const int b = threadIdx.x >> 6, lane = threadIdx.x & 63;
    const int chunk = blockIdx.x;                 // 64 chunks x 64 n each
    const int d0 = lane << 3;
    const float* al = slog + (size_t)b * SLS;
    float acc[8] = {0, 0, 0, 0, 0, 0, 0, 0};
#pragma unroll 4
    for (int i = 0; i < 64; ++i) {
        const int n = chunk * 64 + i;
        const float a = al[n];
        f16x8 v = *(const f16x8*)(qkv + (size_t)(n * 4 + b) * 1536 + 1024 + d0);
#pragma unroll
        for (int j = 0; j < 8; ++j) acc[j] += a * (float)v[j];
    }
    if (chunk == 63) {
        const float a = al[SLS - 1];
        const float* vr = krvr + 2048 + (size_t)b * 512 + d0;
#pragma unroll
        for (int j = 0; j < 8; ++j) acc[j] += a * vr[j];
    }
#pragma unroll
    for (int j = 0; j < 8; ++j) atomicAdd(&star[(size_t)b * 512 + d0 + j], acc[j]);
}

// ---------------- host launch ----------------
extern "C" void kernel_launch(void* const* d_in, const int* in_sizes, int n_in,
                              void* d_out, int out_size, void* d_ws, size_t ws_size,
                              hipStream_t stream) {
    const float* x     = (const float*)d_in[0];
    const float* e     = (const float*)d_in[1];
    const float* relay = (const float*)d_in[2];
    const float* Wq    = (const float*)d_in[3];
    const float* bq    = (const float*)d_in[4];
    const float* Wk    = (const float*)d_in[5];
    const float* bk    = (const float*)d_in[6];
    const float* Wv    = (const float*)d_in[7];
    const float* bv    = (const float*)d_in[8];
    const float* Wo    = (const float*)d_in[9];
    const float* bo    = (const float*)d_in[10];
    float* out = (float*)d_out;

    size_t off = 0;
    auto alloc = [&](size_t bytes) {
        void* p = (char*)d_ws + off;
        off += (bytes + 255) & ~(size_t)255;
        return p;
    };
    _Float16* Wqkv = (_Float16*)alloc((size_t)1536 * 512 * 2);
    _Float16* Wof  = (_Float16*)alloc((size_t)512 * 512 * 2);
    float*    bqkv = (float*)   alloc(1536 * 4);
    _Float16* xh   = (_Float16*)alloc((size_t)M_ROWS * 512 * 2);
    _Float16* eh   = (_Float16*)alloc((size_t)M_ROWS * 512 * 2);
    _Float16* qkv  = (_Float16*)alloc((size_t)M_ROWS * 1536 * 2);
    _Float16* ekv  = (_Float16*)alloc((size_t)M_ROWS * 1024 * 2);
    float*    krvr = (float*)   alloc(2 * 4 * 512 * 4);
    float*    slog = (float*)   alloc((size_t)4 * SLS * 4);
    float*    star = (float*)   alloc(4 * 512 * 4);
    _Float16* ringb = xh;   // alias: xh is dead after the fused qkv/ekv GEMM

    prep<<<PREP_XE_B + PREP_W_B + 1024, 256, 0, stream>>>(
        x, e, Wq, Wk, Wv, Wo, bq, bk, bv, relay,
        xh, eh, Wqkv, Wof, bqkv, krvr, star);

    // fused qkv (128x12=1536 tiles) + ekv (128x8=1024 tiles): 2560 blocks
    GemmP gq { xh, Wqkv,                     bqkv,       qkv, 1536, 12 };
    GemmP ge { eh, Wqkv + (size_t)512 * 512, bqkv + 512, ekv, 1024,  8 };
    gemm2p<1><<<2560, 256, 0, stream>>>(gq, ge, 1536, 320);

    ring_attn<<<M_ROWS / 4, 256, 0, stream>>>(qkv, ekv, krvr, relay, ringb, slog);

    star_softmax<<<4, 1024, 0, stream>>>(relay, krvr, slog);
    star_out<<<64, 256, 0, stream>>>(slog, qkv, krvr, star);

    // merged tail: out-projection (512 gemm tiles) + star_proj (512 blocks)
    GemmP go { ringb, Wof, bo, out, 512, 4 };
    tail_fused<<<1024, 256, 0, stream>>>(go, star, Wo, bo, out + (size_t)M_ROWS * 512);
}

// Round 14
// 149.393 us; speedup vs baseline: 1.3308x; 1.0115x over previous
//
#include <hip/hip_runtime.h>
#include <hip/hip_fp16.h>

#define L_SEQ 4096
#define BATCH 4
#define DIM 512
#define M_ROWS (L_SEQ * BATCH)          // 16384
#define SCALE 0.04419417382415922f      // 1/sqrt(512)
#define SLS 4097                         // star logits per batch (L+1)

typedef __attribute__((ext_vector_type(4))) float f32x4;
typedef __attribute__((ext_vector_type(8))) _Float16 f16x8;
typedef __attribute__((ext_vector_type(4))) _Float16 f16x4;

__device__ inline void gload16(const void* g, void* l) {
    __builtin_amdgcn_global_load_lds(
        (const __attribute__((address_space(1))) void*)g,
        (__attribute__((address_space(3))) void*)l, 16, 0, 0);
}

__device__ inline float wred_sum(float s) {
#pragma unroll
    for (int o = 32; o; o >>= 1) s += __shfl_xor(s, o);
    return s;
}
__device__ inline float wred_max(float s) {
#pragma unroll
    for (int o = 32; o; o >>= 1) s = fmaxf(s, __shfl_xor(s, o));
    return s;
}

// ------- prep: weight f32->f16 + bias pack + relay k/v proj + star zero -------
// r14: x/e conversion REMOVED (fused into gemm2p's A-path). 768 + 1024 blocks.
__global__ __launch_bounds__(256) void prep(
    const float* __restrict__ Wq, const float* __restrict__ Wk,
    const float* __restrict__ Wv, const float* __restrict__ Wo,
    const float* __restrict__ bq, const float* __restrict__ bk, const float* __restrict__ bv,
    const float* __restrict__ relay,
    _Float16* __restrict__ Wqkv, _Float16* __restrict__ Wof, float* __restrict__ bqkv,
    float* __restrict__ krvr, float* __restrict__ star)
{
    const int bid = blockIdx.x;
    if (bid < 768) {                         // weights: 196608 f16x4 items
        const int w = bid * 256 + threadIdx.x;
        const int o = w * 4, r = o >> 9, c = o & 511;
        const float* W = (r < 512) ? Wq : (r < 1024 ? Wk : Wv);
        float4 v = *(const float4*)(W + (size_t)(r & 511) * 512 + c);
        *(f16x4*)(Wqkv + o) = f16x4{ (_Float16)v.x, (_Float16)v.y, (_Float16)v.z, (_Float16)v.w };
        if (o < 262144) {
            float4 u = *(const float4*)(Wo + o);
            *(f16x4*)(Wof + o) = f16x4{ (_Float16)u.x, (_Float16)u.y, (_Float16)u.z, (_Float16)u.w };
        }
        if (w < 1536) bqkv[w] = (w < 512) ? bq[w] : (w < 1024 ? bk[w - 512] : bv[w - 1024]);
    } else {                                 // relay k/v projection (fp32), wave-per-output
        const int o = ((bid - 768) << 2) + (threadIdx.x >> 6);   // 0..4095
        const int lane = threadIdx.x & 63;
        const int sel = o >> 11, rem = o & 2047, b = rem >> 9, j = rem & 511;
        const float* W = sel ? Wv : Wk;
        const float* wr = W + (size_t)j * 512 + lane * 8;
        const float* rp = relay + (size_t)b * 512 + lane * 8;
        float4 w0 = *(const float4*)wr,  w1 = *(const float4*)(wr + 4);
        float4 r0 = *(const float4*)rp,  r1 = *(const float4*)(rp + 4);
        float s = w0.x * r0.x + w0.y * r0.y + w0.z * r0.z + w0.w * r0.w
                + w1.x * r1.x + w1.y * r1.y + w1.z * r1.z + w1.w * r1.w;
        s = wred_sum(s);
        if (lane == 0) {
            krvr[o] = s + (sel ? bv[j] : bk[j]);
            if (o < 2048) star[o] = 0.f;
        }
    }
}

struct GemmP {
    const void*     A;      // gemm2p: f32 [M,512]; tail_fused: f16 [M,512]
    const _Float16* W;      // [N,512] f16 (pre-offset)
    const float*    bias;   // pre-offset
    void*           C;
    int             cstride;
    int             ncols;  // col tiles = N/128
};

// ------- 2-phase 128x128 GEMM, 3-ring; A read as f32 + converted in-kernel ----
// r14: A staged via reg-pipeline (3 named f32x4[4] buffers, statically indexed
// by a 3-step-unrolled loop). z8(t): issue B gload_lds(t+3) + A f32 loads(t+3).
// zone5(t): cvt + ds_write A(t+1) into slot (t+1)%3 (prior readers drained 2
// barriers earlier). FIFO ledger (empty-asm fences pin issue order):
// prologue B0-2,A0-2 (18) -> vmcnt(8) = A0 ready; loop waits 4/6/.../6/0/0.
template<int OUT16>
__global__ __launch_bounds__(256) void gemm2p(GemmP g0, GemmP g1, int n0, int cpx)
{
    __shared__ __align__(16) char smem[49152];
    _Float16* lAb = (_Float16*)smem;             // 3 slices x 4096 f16 (24 KB)
    _Float16* lBb = (_Float16*)(smem + 24576);   // 3 slices x 4096 f16

    const int bid = blockIdx.x;
    const int swz = (bid & 7) * cpx + (bid >> 3);        // bijective: grid%8==0
    const GemmP g = (swz < n0) ? g0 : g1;
    const int l  = (swz < n0) ? swz : swz - n0;
    const int mt = l / g.ncols, nt = l % g.ncols;
    const int row0 = mt * 128, col0 = nt * 128;

    const int tid = threadIdx.x;
    const int wave = tid >> 6, lane = tid & 63;
    const int wm = (wave >> 1) * 64, wn = (wave & 1) * 64;
    const float* Af = (const float*)g.A;

    f32x4 acc[4][4];
#pragma unroll
    for (int i = 0; i < 4; ++i)
#pragma unroll
        for (int j = 0; j < 4; ++j) acc[i][j] = (f32x4)0.f;

    const int idx1 = 256 + tid;
    const int r0_ = tid >> 2,  c0_ = ((tid & 3) ^ ((tid >> 3) & 3)) * 8;
    const int r1_ = idx1 >> 2, c1_ = ((idx1 & 3) ^ ((idx1 >> 3) & 3)) * 8;
    const int ldsb0 = (wave * 64) * 8;
    const int ldsb1 = (256 + wave * 64) * 8;

    auto stageB = [&](int slot, int t) {
        const int k0 = t << 5;
        gload16(g.W + (size_t)(col0 + r0_) * 512 + k0 + c0_, lBb + slot * 4096 + ldsb0);
        gload16(g.W + (size_t)(col0 + r1_) * 512 + k0 + c1_, lBb + slot * 4096 + ldsb1);
    };
    f32x4 a0[4], a1[4], a2[4];
    auto loadA = [&](f32x4* d, int t) {
        const int k0 = t << 5;
        const float* p0 = Af + (size_t)(row0 + r0_) * 512 + k0 + c0_;
        const float* p1 = Af + (size_t)(row0 + r1_) * 512 + k0 + c1_;
        d[0] = *(const f32x4*)p0; d[1] = *(const f32x4*)(p0 + 4);
        d[2] = *(const f32x4*)p1; d[3] = *(const f32x4*)(p1 + 4);
    };
    auto writeA = [&](const f32x4* s, int slot) {
        f16x8 h0 = { (_Float16)s[0][0], (_Float16)s[0][1], (_Float16)s[0][2], (_Float16)s[0][3],
                     (_Float16)s[1][0], (_Float16)s[1][1], (_Float16)s[1][2], (_Float16)s[1][3] };
        f16x8 h1 = { (_Float16)s[2][0], (_Float16)s[2][1], (_Float16)s[2][2], (_Float16)s[2][3],
                     (_Float16)s[3][0], (_Float16)s[3][1], (_Float16)s[3][2], (_Float16)s[3][3] };
        *(f16x8*)(lAb + slot * 4096 + tid * 8) = h0;
        *(f16x8*)(lAb + slot * 4096 + (256 + tid) * 8) = h1;
    };

    // prologue: B0,B1,B2 (6 vmem) then A0,A1,A2 (12 vmem), order pinned
    stageB(0, 0); stageB(1, 1); stageB(2, 2);
    asm volatile("" ::: "memory");
    loadA(a0, 0); asm volatile("" ::: "memory");
    loadA(a1, 1); asm volatile("" ::: "memory");
    loadA(a2, 2);
    asm volatile("s_waitcnt vmcnt(8)" ::: "memory");   // retire B0-2 + a0
    writeA(a0, 0);
    asm volatile("s_waitcnt lgkmcnt(0)" ::: "memory");

    const int rslot = ((lane >> 4) ^ ((lane >> 1) & 3)) * 8;
    const int arb = (wm + (lane & 15)) * 32 + rslot;
    const int brb = (wn + (lane & 15)) * 32 + rslot;

    auto step = [&](int t, int slot, int swrt, f32x4* aW, f32x4* aL) {
        if (t == 0)      asm volatile("s_waitcnt vmcnt(4)" ::: "memory");
        else if (t < 14) asm volatile("s_waitcnt vmcnt(6)" ::: "memory");
        else             asm volatile("s_waitcnt vmcnt(0)" ::: "memory");
        __builtin_amdgcn_s_barrier();                 // tile t staged for all waves
        f16x8 af[4], bfr[4];
#pragma unroll
        for (int i = 0; i < 4; ++i) af[i]  = *(const f16x8*)(lAb + slot * 4096 + arb + i * 512);
#pragma unroll
        for (int i = 0; i < 4; ++i) bfr[i] = *(const f16x8*)(lBb + slot * 4096 + brb + i * 512);
        __builtin_amdgcn_s_setprio(1);
#pragma unroll
        for (int mi = 0; mi < 4; ++mi)
#pragma unroll
            for (int ni = 0; ni < 4; ++ni)
                acc[mi][ni] = __builtin_amdgcn_mfma_f32_16x16x32_f16(
                    af[mi], bfr[ni], acc[mi][ni], 0, 0, 0);
        __builtin_amdgcn_s_setprio(0);
        if (t < 15) writeA(aW, swrt);                 // A(t+1) -> slot (t+1)%3
        asm volatile("s_waitcnt lgkmcnt(0)" ::: "memory");  // reads + write drained
        __builtin_amdgcn_s_barrier();                 // all waves done with tile t
        if (t <= 12) {
            stageB(slot, t + 3);                      // B(t+3) -> slot t%3
            asm volatile("" ::: "memory");
            loadA(aL, t + 3);                         // A(t+3) -> regs
        }
    };
#pragma unroll 1
    for (int tb = 0; tb < 15; tb += 3) {
        step(tb,     0, 1, a1, a0);
        step(tb + 1, 1, 2, a2, a1);
        step(tb + 2, 2, 0, a0, a2);
    }
    step(15, 0, 1, a1, a0);
    // ring LDS dead -> reuse for epilogue bounce

    const int h = lane >> 4, c = lane & 15;
    if (OUT16) {
        _Float16* ep = (_Float16*)smem;               // [128][136] f16 (34816 B)
#pragma unroll
        for (int mi = 0; mi < 4; ++mi)
#pragma unroll
            for (int ni = 0; ni < 4; ++ni) {
                const float bb = g.bias[col0 + wn + ni * 16 + c];
#pragma unroll
                for (int r = 0; r < 4; ++r)
                    ep[(wm + mi * 16 + h * 4 + r) * 136 + wn + ni * 16 + c] =
                        (_Float16)(acc[mi][ni][r] + bb);
            }
        __syncthreads();
        const int rt = tid >> 4, ct = (tid & 15) * 8;
#pragma unroll
        for (int j = 0; j < 8; ++j) {
            const int row = j * 16 + rt;
            f16x8 v = *(const f16x8*)(ep + row * 136 + ct);
            *(f16x8*)((_Float16*)g.C + (size_t)(row0 + row) * g.cstride + col0 + ct) = v;
        }
    } else {
        float* ep = (float*)smem;                     // [64][132] f32 per pass
#pragma unroll
        for (int pass = 0; pass < 2; ++pass) {
            if ((wm == 0) == (pass == 0)) {
#pragma unroll
                for (int mi = 0; mi < 4; ++mi)
#pragma unroll
                    for (int ni = 0; ni < 4; ++ni) {
                        const float bb = g.bias[col0 + wn + ni * 16 + c];
#pragma unroll
                        for (int r = 0; r < 4; ++r)
                            ep[(mi * 16 + h * 4 + r) * 132 + wn + ni * 16 + c] =
                                acc[mi][ni][r] + bb;
                    }
            }
            __syncthreads();
            const int rt = tid >> 5, ct4 = (tid & 31) * 4;
#pragma unroll
            for (int j = 0; j < 8; ++j) {
                const int row = j * 8 + rt;
                f32x4 v = *(const f32x4*)(ep + row * 132 + ct4);
                *(f32x4*)((float*)g.C + (size_t)(row0 + pass * 64 + row) * g.cstride + col0 + ct4) = v;
            }
            if (pass == 0) __syncthreads();
        }
    }
}

// ---- tail: blocks [0,512) = out-projection gemm (f16 A, f32 out); [512,1024) = star_proj ----
__global__ __launch_bounds__(256) void tail_fused(GemmP g,
    const float* __restrict__ star, const float* __restrict__ Wo,
    const float* __restrict__ bo, float* __restrict__ out1)
{
    __shared__ __align__(16) char smem[49152];
    const int bid = blockIdx.x;
    const int tid = threadIdx.x;
    const int lane = tid & 63;

    if (bid >= 512) {                 // ---- star_proj: wave per output ----
        const int o = ((bid - 512) << 2) + (tid >> 6);   // 0..2047
        const int b = o >> 9, j = o & 511;
        const float* sp = star + (size_t)b * 512 + lane * 8;
        const float* wr = Wo + (size_t)j * 512 + lane * 8;
        float4 w0 = *(const float4*)wr,  w1 = *(const float4*)(wr + 4);
        float4 s0 = *(const float4*)sp,  s1 = *(const float4*)(sp + 4);
        float s = w0.x * s0.x + w0.y * s0.y + w0.z * s0.z + w0.w * s0.w
                + w1.x * s1.x + w1.y * s1.y + w1.z * s1.z + w1.w * s1.w;
        s = wred_sum(s);
        if (lane == 0) out1[o] = s + bo[j];
        return;
    }

    // ---- out-projection gemm tile (r9 body, f16 A via gload_lds) ----
    _Float16* lAb = (_Float16*)smem;
    _Float16* lBb = (_Float16*)(smem + 24576);
    const _Float16* Ah = (const _Float16*)g.A;

    const int swz = (bid & 7) * 64 + (bid >> 3);         // bijective over 512
    const int mt = swz / g.ncols, nt = swz % g.ncols;
    const int row0 = mt * 128, col0 = nt * 128;

    const int wave = tid >> 6;
    const int wm = (wave >> 1) * 64, wn = (wave & 1) * 64;

    f32x4 acc[4][4];
#pragma unroll
    for (int i = 0; i < 4; ++i)
#pragma unroll
        for (int j = 0; j < 4; ++j) acc[i][j] = (f32x4)0.f;

    const int idx0 = tid, idx1 = 256 + tid;
    const int r0_ = idx0 >> 2, c0_ = ((idx0 & 3) ^ ((idx0 >> 3) & 3)) * 8;
    const int r1_ = idx1 >> 2, c1_ = ((idx1 & 3) ^ ((idx1 >> 3) & 3)) * 8;
    const int ldsb0 = (wave * 64) * 8;
    const int ldsb1 = (256 + wave * 64) * 8;

    auto stage = [&](int buf, int t) {
        const int k0 = t << 5;
        gload16(Ah + (size_t)(row0 + r0_) * 512 + k0 + c0_, lAb + buf * 4096 + ldsb0);
        gload16(Ah + (size_t)(row0 + r1_) * 512 + k0 + c1_, lAb + buf * 4096 + ldsb1);
        gload16(g.W + (size_t)(col0 + r0_) * 512 + k0 + c0_, lBb + buf * 4096 + ldsb0);
        gload16(g.W + (size_t)(col0 + r1_) * 512 + k0 + c1_, lBb + buf * 4096 + ldsb1);
    };
    stage(0, 0);
    stage(1, 1);
    stage(2, 2);

    const int rslot = ((lane >> 4) ^ ((lane >> 1) & 3)) * 8;
    const int arb = (wm + (lane & 15)) * 32 + rslot;
    const int brb = (wn + (lane & 15)) * 32 + rslot;

    int rs = 0;
#pragma unroll 1
    for (int t = 0; t < 16; ++t) {
        if (t < 14)       asm volatile("s_waitcnt vmcnt(8)" ::: "memory");
        else if (t == 14) asm volatile("s_waitcnt vmcnt(4)" ::: "memory");
        else              asm volatile("s_waitcnt vmcnt(0)" ::: "memory");
        __builtin_amdgcn_s_barrier();
        f16x8 af[4], bfr[4];
#pragma unroll
        for (int i = 0; i < 4; ++i) af[i]  = *(const f16x8*)(lAb + rs * 4096 + arb + i * 512);
#pragma unroll
        for (int i = 0; i < 4; ++i) bfr[i] = *(const f16x8*)(lBb + rs * 4096 + brb + i * 512);
        __builtin_amdgcn_s_setprio(1);
#pragma unroll
        for (int mi = 0; mi < 4; ++mi)
#pragma unroll
            for (int ni = 0; ni < 4; ++ni)
                acc[mi][ni] = __builtin_amdgcn_mfma_f32_16x16x32_f16(
                    af[mi], bfr[ni], acc[mi][ni], 0, 0, 0);
        __builtin_amdgcn_s_setprio(0);
        asm volatile("s_waitcnt lgkmcnt(0)" ::: "memory");
        __builtin_amdgcn_s_barrier();
        if (t + 3 < 16) stage(rs, t + 3);
        rs = (rs == 2) ? 0 : rs + 1;
    }

    const int h = lane >> 4, c = lane & 15;
    float* ep = (float*)smem;                     // [64][132] f32 per pass
#pragma unroll
    for (int pass = 0; pass < 2; ++pass) {
        if ((wm == 0) == (pass == 0)) {
#pragma unroll
            for (int mi = 0; mi < 4; ++mi)
#pragma unroll
                for (int ni = 0; ni < 4; ++ni) {
                    const float bb = g.bias[col0 + wn + ni * 16 + c];
#pragma unroll
                    for (int r = 0; r < 4; ++r)
                        ep[(mi * 16 + h * 4 + r) * 132 + wn + ni * 16 + c] =
                            acc[mi][ni][r] + bb;
                }
        }
        __syncthreads();
        const int rt = tid >> 5, ct4 = (tid & 31) * 4;
#pragma unroll
        for (int j = 0; j < 8; ++j) {
            const int row = j * 8 + rt;
            f32x4 v = *(const f32x4*)(ep + row * 132 + ct4);
            *(f32x4*)((float*)g.C + (size_t)(row0 + pass * 64 + row) * g.cstride + col0 + ct4) = v;
        }
        if (pass == 0) __syncthreads();
    }
}

// ------- ring attention (one wave per (l,b)) + fused star logits -------
__global__ __launch_bounds__(256) void ring_attn(
    const _Float16* __restrict__ qkv,    // [M,1536] q|k|v
    const _Float16* __restrict__ ekv,    // [M,1024] ke|ve
    const float* __restrict__ krvr,      // [2][B][512]
    const float* __restrict__ relay,     // [B,512]
    _Float16* __restrict__ ring,         // [M,512]
    float* __restrict__ slog)            // [B,SLS]
{
    const int wid = (blockIdx.x << 2) + (threadIdx.x >> 6);   // row r = l*B+b
    const int lane = threadIdx.x & 63;
    const int r = wid, b = r & 3, l = r >> 2;
    const int d0 = lane << 3;

    float q[8], rl[8];
    {
        f16x8 t = *(const f16x8*)(qkv + (size_t)r * 1536 + d0);
#pragma unroll
        for (int i = 0; i < 8; ++i) q[i] = (float)t[i];
        const float* rp = relay + (size_t)b * 512 + d0;
        float4 a = *(const float4*)rp, c = *(const float4*)(rp + 4);
        rl[0] = a.x; rl[1] = a.y; rl[2] = a.z; rl[3] = a.w;
        rl[4] = c.x; rl[5] = c.y; rl[6] = c.z; rl[7] = c.w;
    }
    const bool has0 = (l > 0), has2 = (l < L_SEQ - 1);

    auto dotk = [&](const _Float16* kp) -> float {
        f16x8 t = *(const f16x8*)(kp + d0);
        float s = 0.f;
#pragma unroll
        for (int i = 0; i < 8; ++i) s += q[i] * (float)t[i];
        return wred_sum(s);
    };

    float lg[5];
    lg[0] = has0 ? dotk(qkv + (size_t)(r - 4) * 1536 + 512) : 0.f;  // zero key -> logit 0
    lg[2] = has2 ? dotk(qkv + (size_t)(r + 4) * 1536 + 512) : 0.f;
    lg[3] = dotk(ekv + (size_t)r * 1024);
    {   // self k row: ring logit + star logit (relay . k)
        f16x8 t = *(const f16x8*)(qkv + (size_t)r * 1536 + 512 + d0);
        float s1 = 0.f, s2 = 0.f;
#pragma unroll
        for (int i = 0; i < 8; ++i) { float kf = (float)t[i]; s1 += q[i] * kf; s2 += rl[i] * kf; }
#pragma unroll
        for (int o = 32; o; o >>= 1) { s1 += __shfl_xor(s1, o); s2 += __shfl_xor(s2, o); }
        lg[1] = s1;
        if (lane == 0) slog[(size_t)b * SLS + l] = s2 * SCALE;
    }
    {   // relay key
        const float* kp = krvr + (size_t)b * 512 + d0;
        float s = 0.f;
#pragma unroll
        for (int i = 0; i < 8; ++i) s += q[i] * kp[i];
        lg[4] = wred_sum(s);
    }

    float li[5], m = -1e30f;
#pragma unroll
    for (int w = 0; w < 5; ++w) { li[w] = lg[w] * SCALE; m = fmaxf(m, li[w]); }
    float ew[5], Z = 0.f;
#pragma unroll
    for (int w = 0; w < 5; ++w) { ew[w] = expf(li[w] - m); Z += ew[w]; }
    const float inv = 1.f / Z;

    float o8[8] = {0, 0, 0, 0, 0, 0, 0, 0};
    auto addv = [&](const _Float16* vp, float a) {
        f16x8 t = *(const f16x8*)(vp + d0);
#pragma unroll
        for (int i = 0; i < 8; ++i) o8[i] += a * (float)t[i];
    };
    if (has0) addv(qkv + (size_t)(r - 4) * 1536 + 1024, ew[0] * inv);
    addv(qkv + (size_t)r * 1536 + 1024, ew[1] * inv);
    if (has2) addv(qkv + (size_t)(r + 4) * 1536 + 1024, ew[2] * inv);
    addv(ekv + (size_t)r * 1024 + 512, ew[3] * inv);
    {
        const float* vp = krvr + 2048 + (size_t)b * 512 + d0;
        const float a = ew[4] * inv;
#pragma unroll
        for (int i = 0; i < 8; ++i) o8[i] += a * vp[i];
    }
    f16x8 res;
#pragma unroll
    for (int i = 0; i < 8; ++i) res[i] = (_Float16)o8[i];
    *(f16x8*)(ring + (size_t)r * 512 + d0) = res;
}

// ---------------- star softmax: one 1024-thread block per batch ----------------
__global__ __launch_bounds__(1024) void star_softmax(
    const float* __restrict__ relay, const float* __restrict__ krvr,
    float* __restrict__ slog)
{
    const int b = blockIdx.x, t = threadIdx.x, lane = t & 63, w = t >> 6;
    __shared__ float red[16];
    __shared__ float bc[2];
    float* sl = slog + (size_t)b * SLS;

    float p = 0.f;
    if (t < 512) p = relay[(size_t)b * 512 + t] * krvr[(size_t)b * 512 + t];
    p = wred_sum(p);
    if (lane == 0) red[w] = p;
    __syncthreads();
    if (t == 0) { float s = 0.f; for (int i = 0; i < 16; ++i) s += red[i]; bc[0] = s * SCALE; }
    __syncthreads();
    const float selfl = bc[0];
    __syncthreads();

    float v[4];
#pragma unroll
    for (int i = 0; i < 4; ++i) v[i] = sl[t + i * 1024];

    float m = selfl;
#pragma unroll
    for (int i = 0; i < 4; ++i) m = fmaxf(m, v[i]);
    m = wred_max(m);
    if (lane == 0) red[w] = m;
    __syncthreads();
    if (t == 0) { float mm = red[0]; for (int i = 1; i < 16; ++i) mm = fmaxf(mm, red[i]); bc[1] = mm; }
    __syncthreads();
    m = bc[1];

    float ev[4], z = (t == 0) ? expf(selfl - m) : 0.f;
#pragma unroll
    for (int i = 0; i < 4; ++i) { ev[i] = expf(v[i] - m); z += ev[i]; }
    z = wred_sum(z);
    if (lane == 0) red[w] = z;
    __syncthreads();
    if (t == 0) { float s = 0.f; for (int i = 0; i < 16; ++i) s += red[i]; bc[0] = 1.f / s; }
    __syncthreads();
    const float inv = bc[0];

#pragma unroll
    for (int i = 0; i < 4; ++i) sl[t + i * 1024] = ev[i] * inv;
    if (t == 0) sl[SLS - 1] = expf(selfl - m) * inv;
}

// ------- star weighted V-sum: wave per (chunk,b), 64 blocks x 64 n (r9-proven) -------
__global__ __launch_bounds__(256) void star_out(
    const float* __restrict__ slog, const _Float16* __restrict__ qkv,
    const float* __restrict__ krvr, float* __restrict__ star)
{
    const int b = threadIdx.x >> 6, lane = threadIdx.x & 63;
    const int chunk = blockIdx.x;                 // 64 chunks x 64 n each
    const int d0 = lane << 3;
    const float* al = slog + (size_t)b * SLS;
    float acc[8] = {0, 0, 0, 0, 0, 0, 0, 0};
#pragma unroll 4
    for (int i = 0; i < 64; ++i) {
        const int n = chunk * 64 + i;
        const float a = al[n];
        f16x8 v = *(const f16x8*)(qkv + (size_t)(n * 4 + b) * 1536 + 1024 + d0);
#pragma unroll
        for (int j = 0; j < 8; ++j) acc[j] += a * (float)v[j];
    }
    if (chunk == 63) {
        const float a = al[SLS - 1];
        const float* vr = krvr + 2048 + (size_t)b * 512 + d0;
#pragma unroll
        for (int j = 0; j < 8; ++j) acc[j] += a * vr[j];
    }
#pragma unroll
    for (int j = 0; j < 8; ++j) atomicAdd(&star[(size_t)b * 512 + d0 + j], acc[j]);
}

// ---------------- host launch ----------------
extern "C" void kernel_launch(void* const* d_in, const int* in_sizes, int n_in,
                              void* d_out, int out_size, void* d_ws, size_t ws_size,
                              hipStream_t stream) {
    const float* x     = (const float*)d_in[0];
    const float* e     = (const float*)d_in[1];
    const float* relay = (const float*)d_in[2];
    const float* Wq    = (const float*)d_in[3];
    const float* bq    = (const float*)d_in[4];
    const float* Wk    = (const float*)d_in[5];
    const float* bk    = (const float*)d_in[6];
    const float* Wv    = (const float*)d_in[7];
    const float* bv    = (const float*)d_in[8];
    const float* Wo    = (const float*)d_in[9];
    const float* bo    = (const float*)d_in[10];
    float* out = (float*)d_out;

    size_t off = 0;
    auto alloc = [&](size_t bytes) {
        void* p = (char*)d_ws + off;
        off += (bytes + 255) & ~(size_t)255;
        return p;
    };
    _Float16* Wqkv = (_Float16*)alloc((size_t)1536 * 512 * 2);
    _Float16* Wof  = (_Float16*)alloc((size_t)512 * 512 * 2);
    float*    bqkv = (float*)   alloc(1536 * 4);
    _Float16* qkv  = (_Float16*)alloc((size_t)M_ROWS * 1536 * 2);
    _Float16* ekv  = (_Float16*)alloc((size_t)M_ROWS * 1024 * 2);
    _Float16* ringb= (_Float16*)alloc((size_t)M_ROWS * 512 * 2);
    float*    krvr = (float*)   alloc(2 * 4 * 512 * 4);
    float*    slog = (float*)   alloc((size_t)4 * SLS * 4);
    float*    star = (float*)   alloc(4 * 512 * 4);

    prep<<<768 + 1024, 256, 0, stream>>>(
        Wq, Wk, Wv, Wo, bq, bk, bv, relay,
        Wqkv, Wof, bqkv, krvr, star);

    // fused qkv (128x12=1536 tiles) + ekv (128x8=1024 tiles): 2560 blocks
    // A operands are the ORIGINAL f32 x / e (conversion fused into staging).
    GemmP gq { x, Wqkv,                     bqkv,       qkv, 1536, 12 };
    GemmP ge { e, Wqkv + (size_t)512 * 512, bqkv + 512, ekv, 1024,  8 };
    gemm2p<1><<<2560, 256, 0, stream>>>(gq, ge, 1536, 320);

    ring_attn<<<M_ROWS / 4, 256, 0, stream>>>(qkv, ekv, krvr, relay, ringb, slog);

    star_softmax<<<4, 1024, 0, stream>>>(relay, krvr, slog);
    star_out<<<64, 256, 0, stream>>>(slog, qkv, krvr, star);

    // merged tail: out-projection (512 gemm tiles, f16 A) + star_proj (512 blocks)
    GemmP go { ringb, Wof, bo, out, 512, 4 };
    tail_fused<<<1024, 256, 0, stream>>>(go, star, Wo, bo, out + (size_t)M_ROWS * 512);
}

// Round 15
// 149.328 us; speedup vs baseline: 1.3314x; 1.0004x over previous
//
#include <hip/hip_runtime.h>
#include <hip/hip_fp16.h>

#define L_SEQ 4096
#define BATCH 4
#define DIM 512
#define M_ROWS (L_SEQ * BATCH)          // 16384
#define SCALE 0.04419417382415922f      // 1/sqrt(512)
#define SLS 4097                         // star logits per batch (L+1)

typedef __attribute__((ext_vector_type(4))) float f32x4;
typedef __attribute__((ext_vector_type(8))) _Float16 f16x8;
typedef __attribute__((ext_vector_type(4))) _Float16 f16x4;

__device__ inline void gload16(const void* g, void* l) {
    __builtin_amdgcn_global_load_lds(
        (const __attribute__((address_space(1))) void*)g,
        (__attribute__((address_space(3))) void*)l, 16, 0, 0);
}

__device__ inline float wred_sum(float s) {
#pragma unroll
    for (int o = 32; o; o >>= 1) s += __shfl_xor(s, o);
    return s;
}
__device__ inline float wred_max(float s) {
#pragma unroll
    for (int o = 32; o; o >>= 1) s = fmaxf(s, __shfl_xor(s, o));
    return s;
}

// ------- prep: weight f32->f16 + bias pack + relay k/v proj + star zero -------
__global__ __launch_bounds__(256) void prep(
    const float* __restrict__ Wq, const float* __restrict__ Wk,
    const float* __restrict__ Wv, const float* __restrict__ Wo,
    const float* __restrict__ bq, const float* __restrict__ bk, const float* __restrict__ bv,
    const float* __restrict__ relay,
    _Float16* __restrict__ Wqkv, _Float16* __restrict__ Wof, float* __restrict__ bqkv,
    float* __restrict__ krvr, float* __restrict__ star)
{
    const int bid = blockIdx.x;
    if (bid < 768) {                         // weights: 196608 f16x4 items
        const int w = bid * 256 + threadIdx.x;
        const int o = w * 4, r = o >> 9, c = o & 511;
        const float* W = (r < 512) ? Wq : (r < 1024 ? Wk : Wv);
        float4 v = *(const float4*)(W + (size_t)(r & 511) * 512 + c);
        *(f16x4*)(Wqkv + o) = f16x4{ (_Float16)v.x, (_Float16)v.y, (_Float16)v.z, (_Float16)v.w };
        if (o < 262144) {
            float4 u = *(const float4*)(Wo + o);
            *(f16x4*)(Wof + o) = f16x4{ (_Float16)u.x, (_Float16)u.y, (_Float16)u.z, (_Float16)u.w };
        }
        if (w < 1536) bqkv[w] = (w < 512) ? bq[w] : (w < 1024 ? bk[w - 512] : bv[w - 1024]);
    } else {                                 // relay k/v projection (fp32), wave-per-output
        const int o = ((bid - 768) << 2) + (threadIdx.x >> 6);   // 0..4095
        const int lane = threadIdx.x & 63;
        const int sel = o >> 11, rem = o & 2047, b = rem >> 9, j = rem & 511;
        const float* W = sel ? Wv : Wk;
        const float* wr = W + (size_t)j * 512 + lane * 8;
        const float* rp = relay + (size_t)b * 512 + lane * 8;
        float4 w0 = *(const float4*)wr,  w1 = *(const float4*)(wr + 4);
        float4 r0 = *(const float4*)rp,  r1 = *(const float4*)(rp + 4);
        float s = w0.x * r0.x + w0.y * r0.y + w0.z * r0.z + w0.w * r0.w
                + w1.x * r1.x + w1.y * r1.y + w1.z * r1.z + w1.w * r1.w;
        s = wred_sum(s);
        if (lane == 0) {
            krvr[o] = s + (sel ? bv[j] : bk[j]);
            if (o < 2048) star[o] = 0.f;
        }
    }
}

struct GemmP {
    const void*     A;      // gemm2p: f32 [M,512]; tail_fused: f16 [M,512]
    const _Float16* W;      // [N,512] f16 (pre-offset)
    const float*    bias;   // pre-offset
    void*           C;
    int             cstride;
    int             ncols;  // col tiles = N/128
};

// ------- 2-phase 128x128 GEMM, 3-ring; A read as f32 + converted in-kernel ----
// r15 FIX: steady-state wait was vmcnt(6) — but entering step t the outstanding
// ops are stages t+1,t+2 = 12, so vmcnt(6) forced stage t+1 (issued ONE step
// earlier) to complete -> pipeline depth collapsed to 1, full HBM latency
// exposed each step (r14: 107us, MfmaUtil 16%). Correct ledger: vmcnt(12)
// retires exactly stage t. B(t) visibility is additionally guaranteed by the
// compiler's wait before writeA(A(t)) (A regs issued after B(t); FIFO retire).
// Tail: t=14 -> 6, t=15 -> 0.
template<int OUT16>
__global__ __launch_bounds__(256) void gemm2p(GemmP g0, GemmP g1, int n0, int cpx)
{
    __shared__ __align__(16) char smem[49152];
    _Float16* lAb = (_Float16*)smem;             // 3 slices x 4096 f16 (24 KB)
    _Float16* lBb = (_Float16*)(smem + 24576);   // 3 slices x 4096 f16

    const int bid = blockIdx.x;
    const int swz = (bid & 7) * cpx + (bid >> 3);        // bijective: grid%8==0
    const GemmP g = (swz < n0) ? g0 : g1;
    const int l  = (swz < n0) ? swz : swz - n0;
    const int mt = l / g.ncols, nt = l % g.ncols;
    const int row0 = mt * 128, col0 = nt * 128;

    const int tid = threadIdx.x;
    const int wave = tid >> 6, lane = tid & 63;
    const int wm = (wave >> 1) * 64, wn = (wave & 1) * 64;
    const float* Af = (const float*)g.A;

    f32x4 acc[4][4];
#pragma unroll
    for (int i = 0; i < 4; ++i)
#pragma unroll
        for (int j = 0; j < 4; ++j) acc[i][j] = (f32x4)0.f;

    const int idx1 = 256 + tid;
    const int r0_ = tid >> 2,  c0_ = ((tid & 3) ^ ((tid >> 3) & 3)) * 8;
    const int r1_ = idx1 >> 2, c1_ = ((idx1 & 3) ^ ((idx1 >> 3) & 3)) * 8;
    const int ldsb0 = (wave * 64) * 8;
    const int ldsb1 = (256 + wave * 64) * 8;

    auto stageB = [&](int slot, int t) {
        const int k0 = t << 5;
        gload16(g.W + (size_t)(col0 + r0_) * 512 + k0 + c0_, lBb + slot * 4096 + ldsb0);
        gload16(g.W + (size_t)(col0 + r1_) * 512 + k0 + c1_, lBb + slot * 4096 + ldsb1);
    };
    f32x4 a0[4], a1[4], a2[4];
    auto loadA = [&](f32x4* d, int t) {
        const int k0 = t << 5;
        const float* p0 = Af + (size_t)(row0 + r0_) * 512 + k0 + c0_;
        const float* p1 = Af + (size_t)(row0 + r1_) * 512 + k0 + c1_;
        d[0] = *(const f32x4*)p0; d[1] = *(const f32x4*)(p0 + 4);
        d[2] = *(const f32x4*)p1; d[3] = *(const f32x4*)(p1 + 4);
    };
    auto writeA = [&](const f32x4* s, int slot) {
        f16x8 h0 = { (_Float16)s[0][0], (_Float16)s[0][1], (_Float16)s[0][2], (_Float16)s[0][3],
                     (_Float16)s[1][0], (_Float16)s[1][1], (_Float16)s[1][2], (_Float16)s[1][3] };
        f16x8 h1 = { (_Float16)s[2][0], (_Float16)s[2][1], (_Float16)s[2][2], (_Float16)s[2][3],
                     (_Float16)s[3][0], (_Float16)s[3][1], (_Float16)s[3][2], (_Float16)s[3][3] };
        *(f16x8*)(lAb + slot * 4096 + tid * 8) = h0;
        *(f16x8*)(lAb + slot * 4096 + (256 + tid) * 8) = h1;
    };

    // prologue: B0,B1,B2 (6 vmem) then A0,A1,A2 (12 vmem), order pinned
    stageB(0, 0); stageB(1, 1); stageB(2, 2);
    asm volatile("" ::: "memory");
    loadA(a0, 0); asm volatile("" ::: "memory");
    loadA(a1, 1); asm volatile("" ::: "memory");
    loadA(a2, 2);
    asm volatile("s_waitcnt vmcnt(8)" ::: "memory");   // retire B0-2 + a0
    writeA(a0, 0);
    asm volatile("s_waitcnt lgkmcnt(0)" ::: "memory");

    const int rslot = ((lane >> 4) ^ ((lane >> 1) & 3)) * 8;
    const int arb = (wm + (lane & 15)) * 32 + rslot;
    const int brb = (wn + (lane & 15)) * 32 + rslot;

    auto step = [&](int t, int slot, int swrt, f32x4* aW, f32x4* aL) {
        if (t == 0)      asm volatile("s_waitcnt vmcnt(8)"  ::: "memory");
        else if (t < 14) asm volatile("s_waitcnt vmcnt(12)" ::: "memory");  // retire stage t
        else if (t == 14) asm volatile("s_waitcnt vmcnt(6)" ::: "memory");
        else             asm volatile("s_waitcnt vmcnt(0)"  ::: "memory");
        __builtin_amdgcn_s_barrier();                 // tile t staged for all waves
        f16x8 af[4], bfr[4];
#pragma unroll
        for (int i = 0; i < 4; ++i) af[i]  = *(const f16x8*)(lAb + slot * 4096 + arb + i * 512);
#pragma unroll
        for (int i = 0; i < 4; ++i) bfr[i] = *(const f16x8*)(lBb + slot * 4096 + brb + i * 512);
        __builtin_amdgcn_s_setprio(1);
#pragma unroll
        for (int mi = 0; mi < 4; ++mi)
#pragma unroll
            for (int ni = 0; ni < 4; ++ni)
                acc[mi][ni] = __builtin_amdgcn_mfma_f32_16x16x32_f16(
                    af[mi], bfr[ni], acc[mi][ni], 0, 0, 0);
        __builtin_amdgcn_s_setprio(0);
        if (t < 15) writeA(aW, swrt);                 // A(t+1) -> slot (t+1)%3
        asm volatile("s_waitcnt lgkmcnt(0)" ::: "memory");  // reads + write drained
        __builtin_amdgcn_s_barrier();                 // all waves done with tile t
        if (t <= 12) {
            stageB(slot, t + 3);                      // B(t+3) -> slot t%3
            asm volatile("" ::: "memory");
            loadA(aL, t + 3);                         // A(t+3) -> regs
        }
    };
#pragma unroll 1
    for (int tb = 0; tb < 15; tb += 3) {
        step(tb,     0, 1, a1, a0);
        step(tb + 1, 1, 2, a2, a1);
        step(tb + 2, 2, 0, a0, a2);
    }
    step(15, 0, 1, a1, a0);
    // ring LDS dead -> reuse for epilogue bounce

    const int h = lane >> 4, c = lane & 15;
    if (OUT16) {
        _Float16* ep = (_Float16*)smem;               // [128][136] f16 (34816 B)
#pragma unroll
        for (int mi = 0; mi < 4; ++mi)
#pragma unroll
            for (int ni = 0; ni < 4; ++ni) {
                const float bb = g.bias[col0 + wn + ni * 16 + c];
#pragma unroll
                for (int r = 0; r < 4; ++r)
                    ep[(wm + mi * 16 + h * 4 + r) * 136 + wn + ni * 16 + c] =
                        (_Float16)(acc[mi][ni][r] + bb);
            }
        __syncthreads();
        const int rt = tid >> 4, ct = (tid & 15) * 8;
#pragma unroll
        for (int j = 0; j < 8; ++j) {
            const int row = j * 16 + rt;
            f16x8 v = *(const f16x8*)(ep + row * 136 + ct);
            *(f16x8*)((_Float16*)g.C + (size_t)(row0 + row) * g.cstride + col0 + ct) = v;
        }
    } else {
        float* ep = (float*)smem;                     // [64][132] f32 per pass
#pragma unroll
        for (int pass = 0; pass < 2; ++pass) {
            if ((wm == 0) == (pass == 0)) {
#pragma unroll
                for (int mi = 0; mi < 4; ++mi)
#pragma unroll
                    for (int ni = 0; ni < 4; ++ni) {
                        const float bb = g.bias[col0 + wn + ni * 16 + c];
#pragma unroll
                        for (int r = 0; r < 4; ++r)
                            ep[(mi * 16 + h * 4 + r) * 132 + wn + ni * 16 + c] =
                                acc[mi][ni][r] + bb;
                    }
            }
            __syncthreads();
            const int rt = tid >> 5, ct4 = (tid & 31) * 4;
#pragma unroll
            for (int j = 0; j < 8; ++j) {
                const int row = j * 8 + rt;
                f32x4 v = *(const f32x4*)(ep + row * 132 + ct4);
                *(f32x4*)((float*)g.C + (size_t)(row0 + pass * 64 + row) * g.cstride + col0 + ct4) = v;
            }
            if (pass == 0) __syncthreads();
        }
    }
}

// ---- tail: blocks [0,512) = out-projection gemm (f16 A, f32 out); [512,1024) = star_proj ----
__global__ __launch_bounds__(256) void tail_fused(GemmP g,
    const float* __restrict__ star, const float* __restrict__ Wo,
    const float* __restrict__ bo, float* __restrict__ out1)
{
    __shared__ __align__(16) char smem[49152];
    const int bid = blockIdx.x;
    const int tid = threadIdx.x;
    const int lane = tid & 63;

    if (bid >= 512) {                 // ---- star_proj: wave per output ----
        const int o = ((bid - 512) << 2) + (tid >> 6);   // 0..2047
        const int b = o >> 9, j = o & 511;
        const float* sp = star + (size_t)b * 512 + lane * 8;
        const float* wr = Wo + (size_t)j * 512 + lane * 8;
        float4 w0 = *(const float4*)wr,  w1 = *(const float4*)(wr + 4);
        float4 s0 = *(const float4*)sp,  s1 = *(const float4*)(sp + 4);
        float s = w0.x * s0.x + w0.y * s0.y + w0.z * s0.z + w0.w * s0.w
                + w1.x * s1.x + w1.y * s1.y + w1.z * s1.z + w1.w * s1.w;
        s = wred_sum(s);
        if (lane == 0) out1[o] = s + bo[j];
        return;
    }

    // ---- out-projection gemm tile (r9 body, f16 A via gload_lds) ----
    _Float16* lAb = (_Float16*)smem;
    _Float16* lBb = (_Float16*)(smem + 24576);
    const _Float16* Ah = (const _Float16*)g.A;

    const int swz = (bid & 7) * 64 + (bid >> 3);         // bijective over 512
    const int mt = swz / g.ncols, nt = swz % g.ncols;
    const int row0 = mt * 128, col0 = nt * 128;

    const int wave = tid >> 6;
    const int wm = (wave >> 1) * 64, wn = (wave & 1) * 64;

    f32x4 acc[4][4];
#pragma unroll
    for (int i = 0; i < 4; ++i)
#pragma unroll
        for (int j = 0; j < 4; ++j) acc[i][j] = (f32x4)0.f;

    const int idx0 = tid, idx1 = 256 + tid;
    const int r0_ = idx0 >> 2, c0_ = ((idx0 & 3) ^ ((idx0 >> 3) & 3)) * 8;
    const int r1_ = idx1 >> 2, c1_ = ((idx1 & 3) ^ ((idx1 >> 3) & 3)) * 8;
    const int ldsb0 = (wave * 64) * 8;
    const int ldsb1 = (256 + wave * 64) * 8;

    auto stage = [&](int buf, int t) {
        const int k0 = t << 5;
        gload16(Ah + (size_t)(row0 + r0_) * 512 + k0 + c0_, lAb + buf * 4096 + ldsb0);
        gload16(Ah + (size_t)(row0 + r1_) * 512 + k0 + c1_, lAb + buf * 4096 + ldsb1);
        gload16(g.W + (size_t)(col0 + r0_) * 512 + k0 + c0_, lBb + buf * 4096 + ldsb0);
        gload16(g.W + (size_t)(col0 + r1_) * 512 + k0 + c1_, lBb + buf * 4096 + ldsb1);
    };
    stage(0, 0);
    stage(1, 1);
    stage(2, 2);

    const int rslot = ((lane >> 4) ^ ((lane >> 1) & 3)) * 8;
    const int arb = (wm + (lane & 15)) * 32 + rslot;
    const int brb = (wn + (lane & 15)) * 32 + rslot;

    int rs = 0;
#pragma unroll 1
    for (int t = 0; t < 16; ++t) {
        if (t < 14)       asm volatile("s_waitcnt vmcnt(8)" ::: "memory");
        else if (t == 14) asm volatile("s_waitcnt vmcnt(4)" ::: "memory");
        else              asm volatile("s_waitcnt vmcnt(0)" ::: "memory");
        __builtin_amdgcn_s_barrier();
        f16x8 af[4], bfr[4];
#pragma unroll
        for (int i = 0; i < 4; ++i) af[i]  = *(const f16x8*)(lAb + rs * 4096 + arb + i * 512);
#pragma unroll
        for (int i = 0; i < 4; ++i) bfr[i] = *(const f16x8*)(lBb + rs * 4096 + brb + i * 512);
        __builtin_amdgcn_s_setprio(1);
#pragma unroll
        for (int mi = 0; mi < 4; ++mi)
#pragma unroll
            for (int ni = 0; ni < 4; ++ni)
                acc[mi][ni] = __builtin_amdgcn_mfma_f32_16x16x32_f16(
                    af[mi], bfr[ni], acc[mi][ni], 0, 0, 0);
        __builtin_amdgcn_s_setprio(0);
        asm volatile("s_waitcnt lgkmcnt(0)" ::: "memory");
        __builtin_amdgcn_s_barrier();
        if (t + 3 < 16) stage(rs, t + 3);
        rs = (rs == 2) ? 0 : rs + 1;
    }

    const int h = lane >> 4, c = lane & 15;
    float* ep = (float*)smem;                     // [64][132] f32 per pass
#pragma unroll
    for (int pass = 0; pass < 2; ++pass) {
        if ((wm == 0) == (pass == 0)) {
#pragma unroll
            for (int mi = 0; mi < 4; ++mi)
#pragma unroll
                for (int ni = 0; ni < 4; ++ni) {
                    const float bb = g.bias[col0 + wn + ni * 16 + c];
#pragma unroll
                    for (int r = 0; r < 4; ++r)
                        ep[(mi * 16 + h * 4 + r) * 132 + wn + ni * 16 + c] =
                            acc[mi][ni][r] + bb;
                }
        }
        __syncthreads();
        const int rt = tid >> 5, ct4 = (tid & 31) * 4;
#pragma unroll
        for (int j = 0; j < 8; ++j) {
            const int row = j * 8 + rt;
            f32x4 v = *(const f32x4*)(ep + row * 132 + ct4);
            *(f32x4*)((float*)g.C + (size_t)(row0 + pass * 64 + row) * g.cstride + col0 + ct4) = v;
        }
        if (pass == 0) __syncthreads();
    }
}

// ------- ring attention (one wave per (l,b)) + fused star logits -------
__global__ __launch_bounds__(256) void ring_attn(
    const _Float16* __restrict__ qkv,    // [M,1536] q|k|v
    const _Float16* __restrict__ ekv,    // [M,1024] ke|ve
    const float* __restrict__ krvr,      // [2][B][512]
    const float* __restrict__ relay,     // [B,512]
    _Float16* __restrict__ ring,         // [M,512]
    float* __restrict__ slog)            // [B,SLS]
{
    const int wid = (blockIdx.x << 2) + (threadIdx.x >> 6);   // row r = l*B+b
    const int lane = threadIdx.x & 63;
    const int r = wid, b = r & 3, l = r >> 2;
    const int d0 = lane << 3;

    float q[8], rl[8];
    {
        f16x8 t = *(const f16x8*)(qkv + (size_t)r * 1536 + d0);
#pragma unroll
        for (int i = 0; i < 8; ++i) q[i] = (float)t[i];
        const float* rp = relay + (size_t)b * 512 + d0;
        float4 a = *(const float4*)rp, c = *(const float4*)(rp + 4);
        rl[0] = a.x; rl[1] = a.y; rl[2] = a.z; rl[3] = a.w;
        rl[4] = c.x; rl[5] = c.y; rl[6] = c.z; rl[7] = c.w;
    }
    const bool has0 = (l > 0), has2 = (l < L_SEQ - 1);

    auto dotk = [&](const _Float16* kp) -> float {
        f16x8 t = *(const f16x8*)(kp + d0);
        float s = 0.f;
#pragma unroll
        for (int i = 0; i < 8; ++i) s += q[i] * (float)t[i];
        return wred_sum(s);
    };

    float lg[5];
    lg[0] = has0 ? dotk(qkv + (size_t)(r - 4) * 1536 + 512) : 0.f;  // zero key -> logit 0
    lg[2] = has2 ? dotk(qkv + (size_t)(r + 4) * 1536 + 512) : 0.f;
    lg[3] = dotk(ekv + (size_t)r * 1024);
    {   // self k row: ring logit + star logit (relay . k)
        f16x8 t = *(const f16x8*)(qkv + (size_t)r * 1536 + 512 + d0);
        float s1 = 0.f, s2 = 0.f;
#pragma unroll
        for (int i = 0; i < 8; ++i) { float kf = (float)t[i]; s1 += q[i] * kf; s2 += rl[i] * kf; }
#pragma unroll
        for (int o = 32; o; o >>= 1) { s1 += __shfl_xor(s1, o); s2 += __shfl_xor(s2, o); }
        lg[1] = s1;
        if (lane == 0) slog[(size_t)b * SLS + l] = s2 * SCALE;
    }
    {   // relay key
        const float* kp = krvr + (size_t)b * 512 + d0;
        float s = 0.f;
#pragma unroll
        for (int i = 0; i < 8; ++i) s += q[i] * kp[i];
        lg[4] = wred_sum(s);
    }

    float li[5], m = -1e30f;
#pragma unroll
    for (int w = 0; w < 5; ++w) { li[w] = lg[w] * SCALE; m = fmaxf(m, li[w]); }
    float ew[5], Z = 0.f;
#pragma unroll
    for (int w = 0; w < 5; ++w) { ew[w] = expf(li[w] - m); Z += ew[w]; }
    const float inv = 1.f / Z;

    float o8[8] = {0, 0, 0, 0, 0, 0, 0, 0};
    auto addv = [&](const _Float16* vp, float a) {
        f16x8 t = *(const f16x8*)(vp + d0);
#pragma unroll
        for (int i = 0; i < 8; ++i) o8[i] += a * (float)t[i];
    };
    if (has0) addv(qkv + (size_t)(r - 4) * 1536 + 1024, ew[0] * inv);
    addv(qkv + (size_t)r * 1536 + 1024, ew[1] * inv);
    if (has2) addv(qkv + (size_t)(r + 4) * 1536 + 1024, ew[2] * inv);
    addv(ekv + (size_t)r * 1024 + 512, ew[3] * inv);
    {
        const float* vp = krvr + 2048 + (size_t)b * 512 + d0;
        const float a = ew[4] * inv;
#pragma unroll
        for (int i = 0; i < 8; ++i) o8[i] += a * vp[i];
    }
    f16x8 res;
#pragma unroll
    for (int i = 0; i < 8; ++i) res[i] = (_Float16)o8[i];
    *(f16x8*)(ring + (size_t)r * 512 + d0) = res;
}

// ---------------- star softmax: one 1024-thread block per batch ----------------
__global__ __launch_bounds__(1024) void star_softmax(
    const float* __restrict__ relay, const float* __restrict__ krvr,
    float* __restrict__ slog)
{
    const int b = blockIdx.x, t = threadIdx.x, lane = t & 63, w = t >> 6;
    __shared__ float red[16];
    __shared__ float bc[2];
    float* sl = slog + (size_t)b * SLS;

    float p = 0.f;
    if (t < 512) p = relay[(size_t)b * 512 + t] * krvr[(size_t)b * 512 + t];
    p = wred_sum(p);
    if (lane == 0) red[w] = p;
    __syncthreads();
    if (t == 0) { float s = 0.f; for (int i = 0; i < 16; ++i) s += red[i]; bc[0] = s * SCALE; }
    __syncthreads();
    const float selfl = bc[0];
    __syncthreads();

    float v[4];
#pragma unroll
    for (int i = 0; i < 4; ++i) v[i] = sl[t + i * 1024];

    float m = selfl;
#pragma unroll
    for (int i = 0; i < 4; ++i) m = fmaxf(m, v[i]);
    m = wred_max(m);
    if (lane == 0) red[w] = m;
    __syncthreads();
    if (t == 0) { float mm = red[0]; for (int i = 1; i < 16; ++i) mm = fmaxf(mm, red[i]); bc[1] = mm; }
    __syncthreads();
    m = bc[1];

    float ev[4], z = (t == 0) ? expf(selfl - m) : 0.f;
#pragma unroll
    for (int i = 0; i < 4; ++i) { ev[i] = expf(v[i] - m); z += ev[i]; }
    z = wred_sum(z);
    if (lane == 0) red[w] = z;
    __syncthreads();
    if (t == 0) { float s = 0.f; for (int i = 0; i < 16; ++i) s += red[i]; bc[0] = 1.f / s; }
    __syncthreads();
    const float inv = bc[0];

#pragma unroll
    for (int i = 0; i < 4; ++i) sl[t + i * 1024] = ev[i] * inv;
    if (t == 0) sl[SLS - 1] = expf(selfl - m) * inv;
}

// ------- star weighted V-sum: wave per (chunk,b), 64 blocks x 64 n (r9-proven) -------
__global__ __launch_bounds__(256) void star_out(
    const float* __restrict__ slog, const _Float16* __restrict__ qkv,
    const float* __restrict__ krvr, float* __restrict__ star)
{
    const int b = threadIdx.x >> 6, lane = threadIdx.x & 63;
    const int chunk = blockIdx.x;                 // 64 chunks x 64 n each
    const int d0 = lane << 3;
    const float* al = slog + (size_t)b * SLS;
    float acc[8] = {0, 0, 0, 0, 0, 0, 0, 0};
#pragma unroll 4
    for (int i = 0; i < 64; ++i) {
        const int n = chunk * 64 + i;
        const float a = al[n];
        f16x8 v = *(const f16x8*)(qkv + (size_t)(n * 4 + b) * 1536 + 1024 + d0);
#pragma unroll
        for (int j = 0; j < 8; ++j) acc[j] += a * (float)v[j];
    }
    if (chunk == 63) {
        const float a = al[SLS - 1];
        const float* vr = krvr + 2048 + (size_t)b * 512 + d0;
#pragma unroll
        for (int j = 0; j < 8; ++j) acc[j] += a * vr[j];
    }
#pragma unroll
    for (int j = 0; j < 8; ++j) atomicAdd(&star[(size_t)b * 512 + d0 + j], acc[j]);
}

// ---------------- host launch ----------------
extern "C" void kernel_launch(void* const* d_in, const int* in_sizes, int n_in,
                              void* d_out, int out_size, void* d_ws, size_t ws_size,
                              hipStream_t stream) {
    const float* x     = (const float*)d_in[0];
    const float* e     = (const float*)d_in[1];
    const float* relay = (const float*)d_in[2];
    const float* Wq    = (const float*)d_in[3];
    const float* bq    = (const float*)d_in[4];
    const float* Wk    = (const float*)d_in[5];
    const float* bk    = (const float*)d_in[6];
    const float* Wv    = (const float*)d_in[7];
    const float* bv    = (const float*)d_in[8];
    const float* Wo    = (const float*)d_in[9];
    const float* bo    = (const float*)d_in[10];
    float* out = (float*)d_out;

    size_t off = 0;
    auto alloc = [&](size_t bytes) {
        void* p = (char*)d_ws + off;
        off += (bytes + 255) & ~(size_t)255;
        return p;
    };
    _Float16* Wqkv = (_Float16*)alloc((size_t)1536 * 512 * 2);
    _Float16* Wof  = (_Float16*)alloc((size_t)512 * 512 * 2);
    float*    bqkv = (float*)   alloc(1536 * 4);
    _Float16* qkv  = (_Float16*)alloc((size_t)M_ROWS * 1536 * 2);
    _Float16* ekv  = (_Float16*)alloc((size_t)M_ROWS * 1024 * 2);
    _Float16* ringb= (_Float16*)alloc((size_t)M_ROWS * 512 * 2);
    float*    krvr = (float*)   alloc(2 * 4 * 512 * 4);
    float*    slog = (float*)   alloc((size_t)4 * SLS * 4);
    float*    star = (float*)   alloc(4 * 512 * 4);

    prep<<<768 + 1024, 256, 0, stream>>>(
        Wq, Wk, Wv, Wo, bq, bk, bv, relay,
        Wqkv, Wof, bqkv, krvr, star);

    // fused qkv (128x12=1536 tiles) + ekv (128x8=1024 tiles): 2560 blocks
    // A operands are the ORIGINAL f32 x / e (conversion fused into staging).
    GemmP gq { x, Wqkv,                     bqkv,       qkv, 1536, 12 };
    GemmP ge { e, Wqkv + (size_t)512 * 512, bqkv + 512, ekv, 1024,  8 };
    gemm2p<1><<<2560, 256, 0, stream>>>(gq, ge, 1536, 320);

    ring_attn<<<M_ROWS / 4, 256, 0, stream>>>(qkv, ekv, krvr, relay, ringb, slog);

    star_softmax<<<4, 1024, 0, stream>>>(relay, krvr, slog);
    star_out<<<64, 256, 0, stream>>>(slog, qkv, krvr, star);

    // merged tail: out-projection (512 gemm tiles, f16 A) + star_proj (512 blocks)
    GemmP go { ringb, Wof, bo, out, 512, 4 };
    tail_fused<<<1024, 256, 0, stream>>>(go, star, Wo, bo, out + (size_t)M_ROWS * 512);
}